// Round 13
// baseline (279.631 us; speedup 1.0000x reference)
//
#include <hip/hip_runtime.h>
#include <hip/hip_bf16.h>

typedef float f32x4 __attribute__((ext_vector_type(4)));
typedef __bf16 bf16x8 __attribute__((ext_vector_type(8)));

#define MFMA(a,b,c) __builtin_amdgcn_mfma_f32_16x16x32_bf16(a,b,c,0,0,0)

// workspace layout (bytes)
#define WS_A_BF   0x000000   // bf16 8192*128  (h@W1a + edge_b1), row-major [node][fi]
#define WS_B_BF   0x200000   // bf16 8192*128  (h@W1b), frag-chunk: [t][f>>3][c][f&7]
#define WS_W2F    0x400000   // bf16 128*128   edge_w2  frag-major [(ks*8+nt)*512+lane*8+j]
#define WS_C1F    0x408000   // bf16 128*128   coord_w1 frag-major (contiguous after W2F)
#define WS_W1AT   0x410000   // bf16 128*128   edge_w1[0:128]^T   [out][in]
#define WS_W1BT   0x418000   // bf16 128*128   edge_w1[128:256]^T [out][in]
#define WS_VW1T   0x420000   // bf16 128*128   velm_w1^T
#define WS_MW2T   0x428000   // bf16 128*128   mlp_w2^T
#define WS_EWT    0x430000   // bf16 128*32    embed_w^T (K padded 30->32)
#define WS_MW1T   0x432000   // bf16 128*64    mlp_w1^T  (K padded 34->64)
#define WS_W1S    0x436000   // bf16 128       edge_w1 row256+row257
#define WS_BASE   0x436200   // f32 8192*2     vel_scale*vel + zMLP

// k_edge dynamic-LDS layout (bytes) — 68.25 KB -> 2 blocks/CU (16 waves)
#define L_WGT   0        // 65536: W2F(32K) + C1F(32K), frag-major
#define L_ASH   65536    // 2048:  this block's 8 A-rows (8 x 128 bf16)
#define L_LOC   67584    // 512:   loc f32[128]
#define L_B2    68096    // 512
#define L_CB1   68608    // 512
#define L_C2    69120    // 512
#define L_WSS   69632    // 256:   w1s bf16[128]
#define L_TOTAL 69888

// fast silu: v_exp + v_rcp
static __device__ __forceinline__ float silu_f(float x) {
  float e = __expf(-x);
  return x * __builtin_amdgcn_rcpf(1.0f + e);
}

// packed f32x2 -> bf16x2 in one VALU op
static __device__ __forceinline__ unsigned cvt_pk_bf16(float lo, float hi) {
  unsigned r;
  asm("v_cvt_pk_bf16_f32 %0, %1, %2" : "=v"(r) : "v"(lo), "v"(hi));
  return r;
}

// ---------------- kernel 0: weight prep --------------------------------------
__global__ void k_prep(const float* __restrict__ ew1, const float* __restrict__ ew2,
                       const float* __restrict__ cw1, const float* __restrict__ vw1,
                       const float* __restrict__ mw1, const float* __restrict__ mw2,
                       const float* __restrict__ embw, char* __restrict__ ws) {
  int n = blockIdx.x;   // fo 0..127
  int k = threadIdx.x;  // fi 0..127
  // frag-major index: one 16x32 fragment = 512 elements (64 lanes x 8)
  int ks = k >> 5, lgrp = (k >> 3) & 3, j = k & 7, nt = n >> 4, lid = n & 15;
  int fidx = (ks*8 + nt)*512 + (lgrp*16 + lid)*8 + j;
  ((__bf16*)(ws+WS_W2F))[fidx] = (__bf16)ew2[k*128+n];
  ((__bf16*)(ws+WS_C1F))[fidx] = (__bf16)cw1[k*128+n];
  ((__bf16*)(ws+WS_W1AT))[n*128+k] = (__bf16)ew1[k*128+n];
  ((__bf16*)(ws+WS_W1BT))[n*128+k] = (__bf16)ew1[(128+k)*128+n];
  ((__bf16*)(ws+WS_VW1T))[n*128+k] = (__bf16)vw1[k*128+n];
  ((__bf16*)(ws+WS_MW2T))[n*128+k] = (__bf16)mw2[k*128+n];
  if (k < 32) ((__bf16*)(ws+WS_EWT ))[n*32+k] = (k<30) ? (__bf16)embw[k*128+n] : (__bf16)0.0f;
  if (k < 64) ((__bf16*)(ws+WS_MW1T))[n*64+k] = (k<34) ? (__bf16)mw1[k*128+n] : (__bf16)0.0f;
  if (n == 0) ((__bf16*)(ws+WS_W1S))[k] = (__bf16)(ew1[256*128+k] + ew1[257*128+k]);
}

// ---------------- kernel 1: node-level (h, A_pre, B_pre, vel_scale, zMLP) -----
__global__ __launch_bounds__(256) void k_node(
    const float* __restrict__ obs,
    const float* __restrict__ emb_b,   const float* __restrict__ edge_b1,
    const float* __restrict__ velm_b1, const float* __restrict__ velm_w2,
    const float* __restrict__ velm_b2, const float* __restrict__ mlp_b1,
    const float* __restrict__ mlp_b2,  const float* __restrict__ mlp_w3,
    const float* __restrict__ mlp_b3,  char* __restrict__ ws) {
  __shared__ char hsh_all[4*4096];
  const int tid = threadIdx.x;
  const int wid = tid>>6, lane = tid&63, lgrp = lane>>4, lid = lane&15;
  char* hw = hsh_all + wid*4096;   // 16 rows x 256B per wave
  const int nb = blockIdx.x*64 + wid*16;
  const int node = nb + lid;

  const __bf16* EWT  = (const __bf16*)(ws+WS_EWT);
  const __bf16* W1AT = (const __bf16*)(ws+WS_W1AT);
  const __bf16* W1BT = (const __bf16*)(ws+WS_W1BT);
  const __bf16* VW1T = (const __bf16*)(ws+WS_VW1T);
  const __bf16* MW1T = (const __bf16*)(ws+WS_MW1T);
  const __bf16* MW2T = (const __bf16*)(ws+WS_MW2T);
  __bf16* A_bf = (__bf16*)(ws+WS_A_BF);
  __bf16* B_bf = (__bf16*)(ws+WS_B_BF);
  float* baseo = (float*)(ws+WS_BASE);

  f32x4 acc[8];

  // ---- stage 1: h = h_in @ embed_w + emb_b (K=32 padded) ----
  bf16x8 aobs;
  #pragma unroll
  for (int j = 0; j < 8; ++j) {
    int k = lgrp*8 + j;
    aobs[j] = (k < 30) ? (__bf16)obs[node*34 + 4 + k] : (__bf16)0.0f;
  }
  #pragma unroll
  for (int nt = 0; nt < 8; ++nt) acc[nt] = (f32x4){0.f,0.f,0.f,0.f};
  #pragma unroll
  for (int nt = 0; nt < 8; ++nt) {
    bf16x8 bw = *(const bf16x8*)(EWT + (nt*16+lid)*32 + lgrp*8);
    acc[nt] = MFMA(aobs, bw, acc[nt]);
  }
  #pragma unroll
  for (int nt = 0; nt < 8; ++nt) {
    int col = nt*16 + lid;
    #pragma unroll
    for (int e = 0; e < 4; ++e) {
      int rl = lgrp*4 + e;
      *(__bf16*)(hw + rl*256 + ((col*2) ^ ((rl&7)<<4))) = (__bf16)(acc[nt][e] + emb_b[col]);
    }
  }
  bf16x8 ah[4];
  #pragma unroll
  for (int ks = 0; ks < 4; ++ks)
    ah[ks] = *(const bf16x8*)(hw + lid*256 + ((ks*64 + lgrp*16) ^ ((lid&7)<<4)));

  // ---- stage 2: A_pre = h @ W1a + edge_b1 -> ws (bf16, row-major) ----
  #pragma unroll
  for (int nt = 0; nt < 8; ++nt) acc[nt] = (f32x4){0.f,0.f,0.f,0.f};
  #pragma unroll
  for (int ks = 0; ks < 4; ++ks)
    #pragma unroll
    for (int nt = 0; nt < 8; ++nt) {
      bf16x8 bw = *(const bf16x8*)(W1AT + (nt*16+lid)*128 + ks*32 + lgrp*8);
      acc[nt] = MFMA(ah[ks], bw, acc[nt]);
    }
  #pragma unroll
  for (int nt = 0; nt < 8; ++nt) {
    int col = nt*16 + lid;
    #pragma unroll
    for (int e = 0; e < 4; ++e)
      A_bf[(nb + lgrp*4 + e)*128 + col] = (__bf16)(acc[nt][e] + edge_b1[col]);
  }

  // ---- stage 3: B_pre = h @ W1b -> ws (bf16, frag-chunk layout) ----
  #pragma unroll
  for (int nt = 0; nt < 8; ++nt) acc[nt] = (f32x4){0.f,0.f,0.f,0.f};
  #pragma unroll
  for (int ks = 0; ks < 4; ++ks)
    #pragma unroll
    for (int nt = 0; nt < 8; ++nt) {
      bf16x8 bw = *(const bf16x8*)(W1BT + (nt*16+lid)*128 + ks*32 + lgrp*8);
      acc[nt] = MFMA(ah[ks], bw, acc[nt]);
    }
  {
    const int t = blockIdx.x;     // 64 nodes per block == one t
    #pragma unroll
    for (int nt = 0; nt < 8; ++nt) {
      int chunk = nt*2 + (lid>>3), j = lid & 7;
      #pragma unroll
      for (int e = 0; e < 4; ++e) {
        int c = wid*16 + lgrp*4 + e;
        B_bf[(size_t)t*8192 + chunk*512 + c*8 + j] = (__bf16)acc[nt][e];
      }
    }
  }

  // ---- stage 4: vel_scale = silu(h@velm_w1 + b1) @ velm_w2 + b2 ----
  #pragma unroll
  for (int nt = 0; nt < 8; ++nt) acc[nt] = (f32x4){0.f,0.f,0.f,0.f};
  #pragma unroll
  for (int ks = 0; ks < 4; ++ks)
    #pragma unroll
    for (int nt = 0; nt < 8; ++nt) {
      bf16x8 bw = *(const bf16x8*)(VW1T + (nt*16+lid)*128 + ks*32 + lgrp*8);
      acc[nt] = MFMA(ah[ks], bw, acc[nt]);
    }
  float pv[4] = {0.f,0.f,0.f,0.f};
  #pragma unroll
  for (int nt = 0; nt < 8; ++nt) {
    int col = nt*16 + lid;
    float w2 = velm_w2[col], b = velm_b1[col];
    #pragma unroll
    for (int e = 0; e < 4; ++e) pv[e] += silu_f(acc[nt][e] + b) * w2;
  }
  #pragma unroll
  for (int d = 1; d < 16; d <<= 1) {
    #pragma unroll
    for (int e = 0; e < 4; ++e) pv[e] += __shfl_xor(pv[e], d, 64);
  }
  float vs[4];
  #pragma unroll
  for (int e = 0; e < 4; ++e) vs[e] = pv[e] + velm_b2[0];

  // ---- stage 5: z1 = silu(obs @ mlp_w1 + b1) (K=64 padded) ----
  bf16x8 az[2];
  #pragma unroll
  for (int ks2 = 0; ks2 < 2; ++ks2)
    #pragma unroll
    for (int j = 0; j < 8; ++j) {
      int k = ks2*32 + lgrp*8 + j;
      az[ks2][j] = (k < 34) ? (__bf16)obs[node*34 + k] : (__bf16)0.0f;
    }
  #pragma unroll
  for (int nt = 0; nt < 8; ++nt) acc[nt] = (f32x4){0.f,0.f,0.f,0.f};
  #pragma unroll
  for (int ks2 = 0; ks2 < 2; ++ks2)
    #pragma unroll
    for (int nt = 0; nt < 8; ++nt) {
      bf16x8 bw = *(const bf16x8*)(MW1T + (nt*16+lid)*64 + ks2*32 + lgrp*8);
      acc[nt] = MFMA(az[ks2], bw, acc[nt]);
    }
  #pragma unroll
  for (int nt = 0; nt < 8; ++nt) {
    int col = nt*16 + lid;
    float b = mlp_b1[col];
    #pragma unroll
    for (int e = 0; e < 4; ++e) {
      int rl = lgrp*4 + e;
      *(__bf16*)(hw + rl*256 + ((col*2) ^ ((rl&7)<<4))) = (__bf16)silu_f(acc[nt][e] + b);
    }
  }
  bf16x8 az1[4];
  #pragma unroll
  for (int ks = 0; ks < 4; ++ks)
    az1[ks] = *(const bf16x8*)(hw + lid*256 + ((ks*64 + lgrp*16) ^ ((lid&7)<<4)));

  // ---- stage 6: z2 = silu(z1@mlp_w2 + b2); o = z2@mlp_w3 ----
  #pragma unroll
  for (int nt = 0; nt < 8; ++nt) acc[nt] = (f32x4){0.f,0.f,0.f,0.f};
  #pragma unroll
  for (int ks = 0; ks < 4; ++ks)
    #pragma unroll
    for (int nt = 0; nt < 8; ++nt) {
      bf16x8 bw = *(const bf16x8*)(MW2T + (nt*16+lid)*128 + ks*32 + lgrp*8);
      acc[nt] = MFMA(az1[ks], bw, acc[nt]);
    }
  float p0[4] = {0.f,0.f,0.f,0.f}, p1[4] = {0.f,0.f,0.f,0.f};
  #pragma unroll
  for (int nt = 0; nt < 8; ++nt) {
    int col = nt*16 + lid;
    float b = mlp_b2[col], w0 = mlp_w3[col*2], w1 = mlp_w3[col*2+1];
    #pragma unroll
    for (int e = 0; e < 4; ++e) {
      float z2 = silu_f(acc[nt][e] + b);
      p0[e] += z2*w0; p1[e] += z2*w1;
    }
  }
  #pragma unroll
  for (int d = 1; d < 16; d <<= 1) {
    #pragma unroll
    for (int e = 0; e < 4; ++e) { p0[e] += __shfl_xor(p0[e], d, 64); p1[e] += __shfl_xor(p1[e], d, 64); }
  }

  // ---- stage 7: base = vel_scale*vel + zMLP out ----
  if (lid == 0) {
    #pragma unroll
    for (int e = 0; e < 4; ++e) {
      int row = nb + lgrp*4 + e;
      float v0 = obs[row*34+2], v1 = obs[row*34+3];
      baseo[row*2+0] = vs[e]*v0 + p0[e] + mlp_b3[0];
      baseo[row*2+1] = vs[e]*v1 + p1[e] + mlp_b3[1];
    }
  }
}

// ---------------- kernel 2: edge chain + aggregation + output -----------------
// 1024 blocks x 512 threads (8 waves, one r per wave) — R10 config (proven,
// no spill) + two latency fixes: (a) block's 8 A-rows staged in LDS (was a
// global load at every ks head), (b) all 4 Bt fragments preloaded per ct
// (pipelined global loads) with GEMM1 ks loop FULLY unrolled so bv[] indices
// stay compile-time (rule #20). Regs ~95-110 < 128 cap.
__global__ __launch_bounds__(512, 4) void k_edge(
    const float* __restrict__ obs, const float* __restrict__ eps,
    const float* __restrict__ edge_b2, const float* __restrict__ coord_b1,
    const float* __restrict__ coord_w2, const float* __restrict__ coord_b2,
    const float* __restrict__ log_std,
    const char* __restrict__ ws, float* __restrict__ out) {
  extern __shared__ __align__(16) char lds[];
  const int tid = threadIdx.x;
  const int wid = tid>>6, lane = tid&63, lgrp = lane>>4, lid = lane&15;
  const int t = blockIdx.x >> 3, rgrp = blockIdx.x & 7;
  const int rl = rgrp*8 + wid;
  const int r  = t*64 + rl;
  float* locsh = (float*)(lds + L_LOC);
  float* b2sh  = (float*)(lds + L_B2);
  float* cb1sh = (float*)(lds + L_CB1);
  float* c2sh  = (float*)(lds + L_C2);

  const __bf16* A_bf = (const __bf16*)(ws+WS_A_BF);
  const __bf16* Bt   = (const __bf16*)(ws+WS_B_BF) + (size_t)t*8192;
  const float* baseo = (const float*)(ws+WS_BASE);

  // ---- stage weights (64KB) + A-rows (2KB) + consts; single barrier ----
  {
    const uint4* gw = (const uint4*)(ws+WS_W2F);
    uint4* lw = (uint4*)(lds + L_WGT);
    #pragma unroll
    for (int i = 0; i < 8; ++i) lw[tid + i*512] = gw[tid + i*512];
    if (tid < 128) {
      int row = tid >> 4, e16 = tid & 15;
      *(uint4*)(lds + L_ASH + row*256 + e16*16) =
          *(const uint4*)(A_bf + (size_t)(t*64 + rgrp*8 + row)*128 + e16*8);
      locsh[tid] = obs[(size_t)(t*64 + (tid>>1))*34 + (tid&1)];
      b2sh[tid]  = edge_b2[tid];
      cb1sh[tid] = coord_b1[tid];
      c2sh[tid]  = coord_w2[tid];
      ((unsigned short*)(lds+L_WSS))[tid] = ((const unsigned short*)(ws+WS_W1S))[tid];
    }
  }
  __syncthreads();

  const char* W2s = lds + L_WGT;           // 32 frags x 1KB
  const char* C1s = lds + L_WGT + 32768;
  const char* ash = lds + L_ASH + wid*256; // this wave's A-row (128 bf16)
  const char* wss = lds + L_WSS;

  const float cb2 = coord_b2[0];
  const float lr0 = locsh[rl*2], lr1 = locsh[rl*2+1];
  // bpermute byte-addresses: src_lane = (lgrp&1)*32 + cgrp*16 + lid
  const int adr0 = (((lgrp&1)<<5) + lid) << 2;
  const int adr1 = adr0 + (16<<2);

  float agg0 = 0.f, agg1 = 0.f;

  #pragma unroll 1
  for (int ct = 0; ct < 4; ++ct) {
    const int c = ct*16 + lid;          // this lane's edge (B-frag col)
    const float d0 = lr0 - locsh[c*2], d1 = lr1 - locsh[c*2+1];
    const float rad = d0*d0 + d1*d1;

    // preload ALL 4 Bt fragments for this ct (independent, pipelined)
    bf16x8 bv[4];
    #pragma unroll
    for (int ks = 0; ks < 4; ++ks)
      bv[ks] = *(const bf16x8*)(Bt + (ks*4+lgrp)*512 + c*8);

    // single accumulator array reused by both GEMMs (32 AGPR total)
    f32x4 acc[8];

    // ---- GEMM1: m2^T, C-init = edge_b2; FULLY unrolled (bv[] const-indexed) ----
    #pragma unroll
    for (int nt = 0; nt < 8; ++nt)
      acc[nt] = *(const f32x4*)(b2sh + nt*16 + lgrp*4);
    #pragma unroll
    for (int ks = 0; ks < 4; ++ks) {
      bf16x8 aAk = *(const bf16x8*)(ash + ks*64 + lgrp*16);
      bf16x8 wsv = *(const bf16x8*)(wss + ks*64 + lgrp*16);
      bf16x8 a1;
      #pragma unroll
      for (int j = 0; j < 8; ++j) {
        float f = (float)aAk[j] + (float)bv[ks][j] + rad*(float)wsv[j];
        a1[j] = (__bf16)silu_f(f);
      }
      #pragma unroll
      for (int nt = 0; nt < 8; ++nt) {
        bf16x8 bw = *(const bf16x8*)(W2s + ((ks*8+nt)*512 + lane*8)*2);
        acc[nt] = MFMA(bw, a1, acc[nt]);
      }
    }

    // ---- silu(m2) + pack to bf16x2 words (acc dead afterwards) ----
    unsigned pk[8][2];
    #pragma unroll
    for (int nt = 0; nt < 8; ++nt) {
      float s0 = silu_f(acc[nt][0]), s1 = silu_f(acc[nt][1]);
      float s2 = silu_f(acc[nt][2]), s3 = silu_f(acc[nt][3]);
      pk[nt][0] = cvt_pk_bf16(s0, s1);
      pk[nt][1] = cvt_pk_bf16(s2, s3);
    }

    // ---- GEMM2: tc^T, C-init = coord_b1; a2 gathered via bpermute ----
    #pragma unroll
    for (int nt = 0; nt < 8; ++nt)
      acc[nt] = *(const f32x4*)(cb1sh + nt*16 + lgrp*4);
    #pragma unroll    // FULL unroll: pk[] indices must be compile-time (scratch rule)
    for (int ks2 = 0; ks2 < 4; ++ks2) {
      unsigned g[4];
      #pragma unroll
      for (int cg = 0; cg < 2; ++cg)
        #pragma unroll
        for (int p = 0; p < 2; ++p) {
          int a = cg ? adr1 : adr0;
          unsigned vlo = (unsigned)__builtin_amdgcn_ds_bpermute(a, (int)pk[2*ks2][p]);
          unsigned vhi = (unsigned)__builtin_amdgcn_ds_bpermute(a, (int)pk[2*ks2+1][p]);
          g[cg*2+p] = (lgrp < 2) ? vlo : vhi;
        }
      union { unsigned u[4]; bf16x8 v; } cvt;
      cvt.u[0] = g[0]; cvt.u[1] = g[1]; cvt.u[2] = g[2]; cvt.u[3] = g[3];
      bf16x8 a2 = cvt.v;
      #pragma unroll
      for (int nt = 0; nt < 8; ++nt) {
        bf16x8 bw = *(const bf16x8*)(C1s + ((ks2*8+nt)*512 + lane*8)*2);
        acc[nt] = MFMA(bw, a2, acc[nt]);
      }
    }

    // ---- epilogue: cw = silu(tc^T)·c2 summed over rows; rows split by lgrp ----
    float pcw = 0.f;
    #pragma unroll
    for (int nt = 0; nt < 8; ++nt) {
      f32x4 c2v = *(const f32x4*)(c2sh + nt*16 + lgrp*4);
      #pragma unroll
      for (int e = 0; e < 4; ++e)
        pcw += silu_f(acc[nt][e]) * c2v[e];
    }
    pcw += __shfl_xor(pcw, 16, 64);
    pcw += __shfl_xor(pcw, 32, 64);
    float cw = pcw + cb2;
    float s = cw * __builtin_amdgcn_rcpf(__builtin_amdgcn_sqrtf(rad) + 1.0f);
    agg0 += d0*s; agg1 += d1*s;
  }

  // each 16-lane group independently holds all-64-edge partials (edge=lid per ct)
  agg0 += __shfl_xor(agg0, 1, 64); agg1 += __shfl_xor(agg1, 1, 64);
  agg0 += __shfl_xor(agg0, 2, 64); agg1 += __shfl_xor(agg1, 2, 64);
  agg0 += __shfl_xor(agg0, 4, 64); agg1 += __shfl_xor(agg1, 4, 64);
  agg0 += __shfl_xor(agg0, 8, 64); agg1 += __shfl_xor(agg1, 8, 64);

  if (lane == 0) {
    float mu0 = baseo[r*2+0] + agg0;
    float mu1 = baseo[r*2+1] + agg1;
    float ls0 = log_std[0], ls1 = log_std[1];
    float e0 = eps[r*2+0], e1 = eps[r*2+1];
    const float C = 0.9189385332046727f; // 0.5*log(2*pi)
    out[r*4+0] = mu0 + __expf(ls0)*e0;
    out[r*4+1] = mu1 + __expf(ls1)*e1;
    out[r*4+2] = -0.5f*e0*e0 - ls0 - C;
    out[r*4+3] = -0.5f*e1*e1 - ls1 - C;
  }
}

extern "C" void kernel_launch(void* const* d_in, const int* in_sizes, int n_in,
                              void* d_out, int out_size, void* d_ws, size_t ws_size,
                              hipStream_t stream) {
  const float* obs      = (const float*)d_in[0];
  const float* eps      = (const float*)d_in[1];
  const float* embed_w  = (const float*)d_in[2];
  const float* embed_b  = (const float*)d_in[3];
  const float* edge_w1  = (const float*)d_in[4];
  const float* edge_b1  = (const float*)d_in[5];
  const float* edge_w2  = (const float*)d_in[6];
  const float* edge_b2  = (const float*)d_in[7];
  const float* coord_w1 = (const float*)d_in[8];
  const float* coord_b1 = (const float*)d_in[9];
  const float* coord_w2 = (const float*)d_in[10];
  const float* coord_b2 = (const float*)d_in[11];
  const float* velm_w1  = (const float*)d_in[12];
  const float* velm_b1  = (const float*)d_in[13];
  const float* velm_w2  = (const float*)d_in[14];
  const float* velm_b2  = (const float*)d_in[15];
  const float* mlp_w1   = (const float*)d_in[20];
  const float* mlp_b1   = (const float*)d_in[21];
  const float* mlp_w2   = (const float*)d_in[22];
  const float* mlp_b2   = (const float*)d_in[23];
  const float* mlp_w3   = (const float*)d_in[24];
  const float* mlp_b3   = (const float*)d_in[25];
  const float* log_std  = (const float*)d_in[26];
  char* ws = (char*)d_ws;
  float* out = (float*)d_out;

  // allow >64KB dynamic LDS for k_edge (host-side, idempotent, capture-safe)
  hipFuncSetAttribute((const void*)k_edge,
                      hipFuncAttributeMaxDynamicSharedMemorySize, L_TOTAL);

  hipLaunchKernelGGL(k_prep, dim3(128), dim3(128), 0, stream,
                     edge_w1, edge_w2, coord_w1, velm_w1, mlp_w1, mlp_w2, embed_w, ws);
  hipLaunchKernelGGL(k_node, dim3(128), dim3(256), 0, stream,
                     obs, embed_b, edge_b1, velm_b1, velm_w2, velm_b2,
                     mlp_b1, mlp_b2, mlp_w3, mlp_b3, ws);
  hipLaunchKernelGGL(k_edge, dim3(1024), dim3(512), L_TOTAL, stream,
                     obs, eps, edge_b2, coord_b1, coord_w2, coord_b2, log_std, ws, out);
}

// Round 14
// 102.306 us; speedup vs baseline: 2.7333x; 2.7333x over previous
//
#include <hip/hip_runtime.h>
#include <hip/hip_bf16.h>

typedef float f32x4 __attribute__((ext_vector_type(4)));
typedef __bf16 bf16x8 __attribute__((ext_vector_type(8)));

#define MFMA(a,b,c) __builtin_amdgcn_mfma_f32_16x16x32_bf16(a,b,c,0,0,0)

// workspace layout (bytes)
#define WS_A_BF   0x000000   // bf16 8192*128  (h@W1a + edge_b1), row-major [node][fi]
#define WS_B_BF   0x200000   // bf16 8192*128  (h@W1b), frag-chunk: [t][f>>3][c][f&7]
#define WS_W2F    0x400000   // bf16 128*128   edge_w2  frag-major [(ks*8+nt)*512+lane*8+j]
#define WS_C1F    0x408000   // bf16 128*128   coord_w1 frag-major (contiguous after W2F)
#define WS_W1AT   0x410000   // bf16 128*128   edge_w1[0:128]^T   [out][in]
#define WS_W1BT   0x418000   // bf16 128*128   edge_w1[128:256]^T [out][in]
#define WS_VW1T   0x420000   // bf16 128*128   velm_w1^T
#define WS_MW2T   0x428000   // bf16 128*128   mlp_w2^T
#define WS_EWT    0x430000   // bf16 128*32    embed_w^T (K padded 30->32)
#define WS_MW1T   0x432000   // bf16 128*64    mlp_w1^T  (K padded 34->64)
#define WS_W1S    0x436000   // bf16 128       edge_w1 row256+row257
#define WS_BASE   0x436200   // f32 8192*2     vel_scale*vel + zMLP

// k_edge dynamic-LDS layout (bytes) — 68.25 KB -> 2 blocks/CU (16 waves)
#define L_WGT   0        // 65536: W2F(32K) + C1F(32K), frag-major
#define L_ASH   65536    // 2048:  this block's 8 A-rows (8 x 128 bf16)
#define L_LOC   67584    // 512:   loc f32[128]
#define L_B2    68096    // 512
#define L_CB1   68608    // 512
#define L_C2    69120    // 512
#define L_WSS   69632    // 256:   w1s bf16[128]
#define L_TOTAL 69888

// fast silu: v_exp + v_rcp
static __device__ __forceinline__ float silu_f(float x) {
  float e = __expf(-x);
  return x * __builtin_amdgcn_rcpf(1.0f + e);
}

// packed f32x2 -> bf16x2 in one VALU op
static __device__ __forceinline__ unsigned cvt_pk_bf16(float lo, float hi) {
  unsigned r;
  asm("v_cvt_pk_bf16_f32 %0, %1, %2" : "=v"(r) : "v"(lo), "v"(hi));
  return r;
}

// ---------------- kernel 0: weight prep --------------------------------------
__global__ void k_prep(const float* __restrict__ ew1, const float* __restrict__ ew2,
                       const float* __restrict__ cw1, const float* __restrict__ vw1,
                       const float* __restrict__ mw1, const float* __restrict__ mw2,
                       const float* __restrict__ embw, char* __restrict__ ws) {
  int n = blockIdx.x;   // fo 0..127
  int k = threadIdx.x;  // fi 0..127
  // frag-major index: one 16x32 fragment = 512 elements (64 lanes x 8)
  int ks = k >> 5, lgrp = (k >> 3) & 3, j = k & 7, nt = n >> 4, lid = n & 15;
  int fidx = (ks*8 + nt)*512 + (lgrp*16 + lid)*8 + j;
  ((__bf16*)(ws+WS_W2F))[fidx] = (__bf16)ew2[k*128+n];
  ((__bf16*)(ws+WS_C1F))[fidx] = (__bf16)cw1[k*128+n];
  ((__bf16*)(ws+WS_W1AT))[n*128+k] = (__bf16)ew1[k*128+n];
  ((__bf16*)(ws+WS_W1BT))[n*128+k] = (__bf16)ew1[(128+k)*128+n];
  ((__bf16*)(ws+WS_VW1T))[n*128+k] = (__bf16)vw1[k*128+n];
  ((__bf16*)(ws+WS_MW2T))[n*128+k] = (__bf16)mw2[k*128+n];
  if (k < 32) ((__bf16*)(ws+WS_EWT ))[n*32+k] = (k<30) ? (__bf16)embw[k*128+n] : (__bf16)0.0f;
  if (k < 64) ((__bf16*)(ws+WS_MW1T))[n*64+k] = (k<34) ? (__bf16)mw1[k*128+n] : (__bf16)0.0f;
  if (n == 0) ((__bf16*)(ws+WS_W1S))[k] = (__bf16)(ew1[256*128+k] + ew1[257*128+k]);
}

// ---------------- kernel 1: node-level (h, A_pre, B_pre, vel_scale, zMLP) -----
__global__ __launch_bounds__(256) void k_node(
    const float* __restrict__ obs,
    const float* __restrict__ emb_b,   const float* __restrict__ edge_b1,
    const float* __restrict__ velm_b1, const float* __restrict__ velm_w2,
    const float* __restrict__ velm_b2, const float* __restrict__ mlp_b1,
    const float* __restrict__ mlp_b2,  const float* __restrict__ mlp_w3,
    const float* __restrict__ mlp_b3,  char* __restrict__ ws) {
  __shared__ char hsh_all[4*4096];
  const int tid = threadIdx.x;
  const int wid = tid>>6, lane = tid&63, lgrp = lane>>4, lid = lane&15;
  char* hw = hsh_all + wid*4096;   // 16 rows x 256B per wave
  const int nb = blockIdx.x*64 + wid*16;
  const int node = nb + lid;

  const __bf16* EWT  = (const __bf16*)(ws+WS_EWT);
  const __bf16* W1AT = (const __bf16*)(ws+WS_W1AT);
  const __bf16* W1BT = (const __bf16*)(ws+WS_W1BT);
  const __bf16* VW1T = (const __bf16*)(ws+WS_VW1T);
  const __bf16* MW1T = (const __bf16*)(ws+WS_MW1T);
  const __bf16* MW2T = (const __bf16*)(ws+WS_MW2T);
  __bf16* A_bf = (__bf16*)(ws+WS_A_BF);
  __bf16* B_bf = (__bf16*)(ws+WS_B_BF);
  float* baseo = (float*)(ws+WS_BASE);

  f32x4 acc[8];

  // ---- stage 1: h = h_in @ embed_w + emb_b (K=32 padded) ----
  bf16x8 aobs;
  #pragma unroll
  for (int j = 0; j < 8; ++j) {
    int k = lgrp*8 + j;
    aobs[j] = (k < 30) ? (__bf16)obs[node*34 + 4 + k] : (__bf16)0.0f;
  }
  #pragma unroll
  for (int nt = 0; nt < 8; ++nt) acc[nt] = (f32x4){0.f,0.f,0.f,0.f};
  #pragma unroll
  for (int nt = 0; nt < 8; ++nt) {
    bf16x8 bw = *(const bf16x8*)(EWT + (nt*16+lid)*32 + lgrp*8);
    acc[nt] = MFMA(aobs, bw, acc[nt]);
  }
  #pragma unroll
  for (int nt = 0; nt < 8; ++nt) {
    int col = nt*16 + lid;
    #pragma unroll
    for (int e = 0; e < 4; ++e) {
      int rl = lgrp*4 + e;
      *(__bf16*)(hw + rl*256 + ((col*2) ^ ((rl&7)<<4))) = (__bf16)(acc[nt][e] + emb_b[col]);
    }
  }
  bf16x8 ah[4];
  #pragma unroll
  for (int ks = 0; ks < 4; ++ks)
    ah[ks] = *(const bf16x8*)(hw + lid*256 + ((ks*64 + lgrp*16) ^ ((lid&7)<<4)));

  // ---- stage 2: A_pre = h @ W1a + edge_b1 -> ws (bf16, row-major) ----
  #pragma unroll
  for (int nt = 0; nt < 8; ++nt) acc[nt] = (f32x4){0.f,0.f,0.f,0.f};
  #pragma unroll
  for (int ks = 0; ks < 4; ++ks)
    #pragma unroll
    for (int nt = 0; nt < 8; ++nt) {
      bf16x8 bw = *(const bf16x8*)(W1AT + (nt*16+lid)*128 + ks*32 + lgrp*8);
      acc[nt] = MFMA(ah[ks], bw, acc[nt]);
    }
  #pragma unroll
  for (int nt = 0; nt < 8; ++nt) {
    int col = nt*16 + lid;
    #pragma unroll
    for (int e = 0; e < 4; ++e)
      A_bf[(nb + lgrp*4 + e)*128 + col] = (__bf16)(acc[nt][e] + edge_b1[col]);
  }

  // ---- stage 3: B_pre = h @ W1b -> ws (bf16, frag-chunk layout) ----
  #pragma unroll
  for (int nt = 0; nt < 8; ++nt) acc[nt] = (f32x4){0.f,0.f,0.f,0.f};
  #pragma unroll
  for (int ks = 0; ks < 4; ++ks)
    #pragma unroll
    for (int nt = 0; nt < 8; ++nt) {
      bf16x8 bw = *(const bf16x8*)(W1BT + (nt*16+lid)*128 + ks*32 + lgrp*8);
      acc[nt] = MFMA(ah[ks], bw, acc[nt]);
    }
  {
    const int t = blockIdx.x;     // 64 nodes per block == one t
    #pragma unroll
    for (int nt = 0; nt < 8; ++nt) {
      int chunk = nt*2 + (lid>>3), j = lid & 7;
      #pragma unroll
      for (int e = 0; e < 4; ++e) {
        int c = wid*16 + lgrp*4 + e;
        B_bf[(size_t)t*8192 + chunk*512 + c*8 + j] = (__bf16)acc[nt][e];
      }
    }
  }

  // ---- stage 4: vel_scale = silu(h@velm_w1 + b1) @ velm_w2 + b2 ----
  #pragma unroll
  for (int nt = 0; nt < 8; ++nt) acc[nt] = (f32x4){0.f,0.f,0.f,0.f};
  #pragma unroll
  for (int ks = 0; ks < 4; ++ks)
    #pragma unroll
    for (int nt = 0; nt < 8; ++nt) {
      bf16x8 bw = *(const bf16x8*)(VW1T + (nt*16+lid)*128 + ks*32 + lgrp*8);
      acc[nt] = MFMA(ah[ks], bw, acc[nt]);
    }
  float pv[4] = {0.f,0.f,0.f,0.f};
  #pragma unroll
  for (int nt = 0; nt < 8; ++nt) {
    int col = nt*16 + lid;
    float w2 = velm_w2[col], b = velm_b1[col];
    #pragma unroll
    for (int e = 0; e < 4; ++e) pv[e] += silu_f(acc[nt][e] + b) * w2;
  }
  #pragma unroll
  for (int d = 1; d < 16; d <<= 1) {
    #pragma unroll
    for (int e = 0; e < 4; ++e) pv[e] += __shfl_xor(pv[e], d, 64);
  }
  float vs[4];
  #pragma unroll
  for (int e = 0; e < 4; ++e) vs[e] = pv[e] + velm_b2[0];

  // ---- stage 5: z1 = silu(obs @ mlp_w1 + b1) (K=64 padded) ----
  bf16x8 az[2];
  #pragma unroll
  for (int ks2 = 0; ks2 < 2; ++ks2)
    #pragma unroll
    for (int j = 0; j < 8; ++j) {
      int k = ks2*32 + lgrp*8 + j;
      az[ks2][j] = (k < 34) ? (__bf16)obs[node*34 + k] : (__bf16)0.0f;
    }
  #pragma unroll
  for (int nt = 0; nt < 8; ++nt) acc[nt] = (f32x4){0.f,0.f,0.f,0.f};
  #pragma unroll
  for (int ks2 = 0; ks2 < 2; ++ks2)
    #pragma unroll
    for (int nt = 0; nt < 8; ++nt) {
      bf16x8 bw = *(const bf16x8*)(MW1T + (nt*16+lid)*64 + ks2*32 + lgrp*8);
      acc[nt] = MFMA(az[ks2], bw, acc[nt]);
    }
  #pragma unroll
  for (int nt = 0; nt < 8; ++nt) {
    int col = nt*16 + lid;
    float b = mlp_b1[col];
    #pragma unroll
    for (int e = 0; e < 4; ++e) {
      int rl = lgrp*4 + e;
      *(__bf16*)(hw + rl*256 + ((col*2) ^ ((rl&7)<<4))) = (__bf16)silu_f(acc[nt][e] + b);
    }
  }
  bf16x8 az1[4];
  #pragma unroll
  for (int ks = 0; ks < 4; ++ks)
    az1[ks] = *(const bf16x8*)(hw + lid*256 + ((ks*64 + lgrp*16) ^ ((lid&7)<<4)));

  // ---- stage 6: z2 = silu(z1@mlp_w2 + b2); o = z2@mlp_w3 ----
  #pragma unroll
  for (int nt = 0; nt < 8; ++nt) acc[nt] = (f32x4){0.f,0.f,0.f,0.f};
  #pragma unroll
  for (int ks = 0; ks < 4; ++ks)
    #pragma unroll
    for (int nt = 0; nt < 8; ++nt) {
      bf16x8 bw = *(const bf16x8*)(MW2T + (nt*16+lid)*128 + ks*32 + lgrp*8);
      acc[nt] = MFMA(az1[ks], bw, acc[nt]);
    }
  float p0[4] = {0.f,0.f,0.f,0.f}, p1[4] = {0.f,0.f,0.f,0.f};
  #pragma unroll
  for (int nt = 0; nt < 8; ++nt) {
    int col = nt*16 + lid;
    float b = mlp_b2[col], w0 = mlp_w3[col*2], w1 = mlp_w3[col*2+1];
    #pragma unroll
    for (int e = 0; e < 4; ++e) {
      float z2 = silu_f(acc[nt][e] + b);
      p0[e] += z2*w0; p1[e] += z2*w1;
    }
  }
  #pragma unroll
  for (int d = 1; d < 16; d <<= 1) {
    #pragma unroll
    for (int e = 0; e < 4; ++e) { p0[e] += __shfl_xor(p0[e], d, 64); p1[e] += __shfl_xor(p1[e], d, 64); }
  }

  // ---- stage 7: base = vel_scale*vel + zMLP out ----
  if (lid == 0) {
    #pragma unroll
    for (int e = 0; e < 4; ++e) {
      int row = nb + lgrp*4 + e;
      float v0 = obs[row*34+2], v1 = obs[row*34+3];
      baseo[row*2+0] = vs[e]*v0 + p0[e] + mlp_b3[0];
      baseo[row*2+1] = vs[e]*v1 + p1[e] + mlp_b3[1];
    }
  }
}

// ---------------- kernel 2: edge chain + aggregation + output -----------------
// 1024 blocks x 512 threads (8 waves, one r per wave) — EXACT R10 structure
// (proven 82us, no spill: GEMM1 ks-loop unroll-1, per-iter bv load, single
// acc[8]) with ONE change: the block's 8 A-rows staged in LDS so GEMM1's
// per-ks aAk read is a ~120cy ds_read instead of a ~200-400cy global load.
__global__ __launch_bounds__(512, 4) void k_edge(
    const float* __restrict__ obs, const float* __restrict__ eps,
    const float* __restrict__ edge_b2, const float* __restrict__ coord_b1,
    const float* __restrict__ coord_w2, const float* __restrict__ coord_b2,
    const float* __restrict__ log_std,
    const char* __restrict__ ws, float* __restrict__ out) {
  extern __shared__ __align__(16) char lds[];
  const int tid = threadIdx.x;
  const int wid = tid>>6, lane = tid&63, lgrp = lane>>4, lid = lane&15;
  const int t = blockIdx.x >> 3, rgrp = blockIdx.x & 7;
  const int rl = rgrp*8 + wid;
  const int r  = t*64 + rl;
  float* locsh = (float*)(lds + L_LOC);
  float* b2sh  = (float*)(lds + L_B2);
  float* cb1sh = (float*)(lds + L_CB1);
  float* c2sh  = (float*)(lds + L_C2);

  const __bf16* A_bf = (const __bf16*)(ws+WS_A_BF);
  const __bf16* Bt   = (const __bf16*)(ws+WS_B_BF) + (size_t)t*8192;
  const float* baseo = (const float*)(ws+WS_BASE);

  // ---- stage weights (64KB) + A-rows (2KB) + consts; single barrier ----
  {
    const uint4* gw = (const uint4*)(ws+WS_W2F);
    uint4* lw = (uint4*)(lds + L_WGT);
    #pragma unroll
    for (int i = 0; i < 8; ++i) lw[tid + i*512] = gw[tid + i*512];
    if (tid < 128) {
      int row = tid >> 4, e16 = tid & 15;
      *(uint4*)(lds + L_ASH + row*256 + e16*16) =
          *(const uint4*)(A_bf + (size_t)(t*64 + rgrp*8 + row)*128 + e16*8);
      locsh[tid] = obs[(size_t)(t*64 + (tid>>1))*34 + (tid&1)];
      b2sh[tid]  = edge_b2[tid];
      cb1sh[tid] = coord_b1[tid];
      c2sh[tid]  = coord_w2[tid];
      ((unsigned short*)(lds+L_WSS))[tid] = ((const unsigned short*)(ws+WS_W1S))[tid];
    }
  }
  __syncthreads();

  const char* W2s = lds + L_WGT;           // 32 frags x 1KB
  const char* C1s = lds + L_WGT + 32768;
  const char* ash = lds + L_ASH + wid*256; // this wave's A-row (128 bf16)
  const char* wss = lds + L_WSS;

  const float cb2 = coord_b2[0];
  const float lr0 = locsh[rl*2], lr1 = locsh[rl*2+1];
  // bpermute byte-addresses: src_lane = (lgrp&1)*32 + cgrp*16 + lid
  const int adr0 = (((lgrp&1)<<5) + lid) << 2;
  const int adr1 = adr0 + (16<<2);

  float agg0 = 0.f, agg1 = 0.f;

  #pragma unroll 1
  for (int ct = 0; ct < 4; ++ct) {
    const int c = ct*16 + lid;          // this lane's edge (B-frag col)
    const float d0 = lr0 - locsh[c*2], d1 = lr1 - locsh[c*2+1];
    const float rad = d0*d0 + d1*d1;

    // single accumulator array reused by both GEMMs (32 AGPR total)
    f32x4 acc[8];

    // ---- GEMM1: m2^T, C-init = edge_b2; unroll-1 (bounded live set) ----
    #pragma unroll
    for (int nt = 0; nt < 8; ++nt)
      acc[nt] = *(const f32x4*)(b2sh + nt*16 + lgrp*4);
    #pragma unroll 1
    for (int ks = 0; ks < 4; ++ks) {
      bf16x8 aAk = *(const bf16x8*)(ash + ks*64 + lgrp*16);
      bf16x8 wsv = *(const bf16x8*)(wss + ks*64 + lgrp*16);
      bf16x8 bv  = *(const bf16x8*)(Bt + (ks*4+lgrp)*512 + c*8);
      bf16x8 a1;
      #pragma unroll
      for (int j = 0; j < 8; ++j) {
        float f = (float)aAk[j] + (float)bv[j] + rad*(float)wsv[j];
        a1[j] = (__bf16)silu_f(f);
      }
      #pragma unroll
      for (int nt = 0; nt < 8; ++nt) {
        bf16x8 bw = *(const bf16x8*)(W2s + ((ks*8+nt)*512 + lane*8)*2);
        acc[nt] = MFMA(bw, a1, acc[nt]);
      }
    }

    // ---- silu(m2) + pack to bf16x2 words (acc dead afterwards) ----
    unsigned pk[8][2];
    #pragma unroll
    for (int nt = 0; nt < 8; ++nt) {
      float s0 = silu_f(acc[nt][0]), s1 = silu_f(acc[nt][1]);
      float s2 = silu_f(acc[nt][2]), s3 = silu_f(acc[nt][3]);
      pk[nt][0] = cvt_pk_bf16(s0, s1);
      pk[nt][1] = cvt_pk_bf16(s2, s3);
    }

    // ---- GEMM2: tc^T, C-init = coord_b1; a2 gathered via bpermute ----
    #pragma unroll
    for (int nt = 0; nt < 8; ++nt)
      acc[nt] = *(const f32x4*)(cb1sh + nt*16 + lgrp*4);
    #pragma unroll    // FULL unroll: pk[] indices must be compile-time (scratch rule)
    for (int ks2 = 0; ks2 < 4; ++ks2) {
      unsigned g[4];
      #pragma unroll
      for (int cg = 0; cg < 2; ++cg)
        #pragma unroll
        for (int p = 0; p < 2; ++p) {
          int a = cg ? adr1 : adr0;
          unsigned vlo = (unsigned)__builtin_amdgcn_ds_bpermute(a, (int)pk[2*ks2][p]);
          unsigned vhi = (unsigned)__builtin_amdgcn_ds_bpermute(a, (int)pk[2*ks2+1][p]);
          g[cg*2+p] = (lgrp < 2) ? vlo : vhi;
        }
      union { unsigned u[4]; bf16x8 v; } cvt;
      cvt.u[0] = g[0]; cvt.u[1] = g[1]; cvt.u[2] = g[2]; cvt.u[3] = g[3];
      bf16x8 a2 = cvt.v;
      #pragma unroll
      for (int nt = 0; nt < 8; ++nt) {
        bf16x8 bw = *(const bf16x8*)(C1s + ((ks2*8+nt)*512 + lane*8)*2);
        acc[nt] = MFMA(bw, a2, acc[nt]);
      }
    }

    // ---- epilogue: cw = silu(tc^T)·c2 summed over rows; rows split by lgrp ----
    float pcw = 0.f;
    #pragma unroll
    for (int nt = 0; nt < 8; ++nt) {
      f32x4 c2v = *(const f32x4*)(c2sh + nt*16 + lgrp*4);
      #pragma unroll
      for (int e = 0; e < 4; ++e)
        pcw += silu_f(acc[nt][e]) * c2v[e];
    }
    pcw += __shfl_xor(pcw, 16, 64);
    pcw += __shfl_xor(pcw, 32, 64);
    float cw = pcw + cb2;
    float s = cw * __builtin_amdgcn_rcpf(__builtin_amdgcn_sqrtf(rad) + 1.0f);
    agg0 += d0*s; agg1 += d1*s;
  }

  // each 16-lane group independently holds all-64-edge partials (edge=lid per ct)
  agg0 += __shfl_xor(agg0, 1, 64); agg1 += __shfl_xor(agg1, 1, 64);
  agg0 += __shfl_xor(agg0, 2, 64); agg1 += __shfl_xor(agg1, 2, 64);
  agg0 += __shfl_xor(agg0, 4, 64); agg1 += __shfl_xor(agg1, 4, 64);
  agg0 += __shfl_xor(agg0, 8, 64); agg1 += __shfl_xor(agg1, 8, 64);

  if (lane == 0) {
    float mu0 = baseo[r*2+0] + agg0;
    float mu1 = baseo[r*2+1] + agg1;
    float ls0 = log_std[0], ls1 = log_std[1];
    float e0 = eps[r*2+0], e1 = eps[r*2+1];
    const float C = 0.9189385332046727f; // 0.5*log(2*pi)
    out[r*4+0] = mu0 + __expf(ls0)*e0;
    out[r*4+1] = mu1 + __expf(ls1)*e1;
    out[r*4+2] = -0.5f*e0*e0 - ls0 - C;
    out[r*4+3] = -0.5f*e1*e1 - ls1 - C;
  }
}

extern "C" void kernel_launch(void* const* d_in, const int* in_sizes, int n_in,
                              void* d_out, int out_size, void* d_ws, size_t ws_size,
                              hipStream_t stream) {
  const float* obs      = (const float*)d_in[0];
  const float* eps      = (const float*)d_in[1];
  const float* embed_w  = (const float*)d_in[2];
  const float* embed_b  = (const float*)d_in[3];
  const float* edge_w1  = (const float*)d_in[4];
  const float* edge_b1  = (const float*)d_in[5];
  const float* edge_w2  = (const float*)d_in[6];
  const float* edge_b2  = (const float*)d_in[7];
  const float* coord_w1 = (const float*)d_in[8];
  const float* coord_b1 = (const float*)d_in[9];
  const float* coord_w2 = (const float*)d_in[10];
  const float* coord_b2 = (const float*)d_in[11];
  const float* velm_w1  = (const float*)d_in[12];
  const float* velm_b1  = (const float*)d_in[13];
  const float* velm_w2  = (const float*)d_in[14];
  const float* velm_b2  = (const float*)d_in[15];
  const float* mlp_w1   = (const float*)d_in[20];
  const float* mlp_b1   = (const float*)d_in[21];
  const float* mlp_w2   = (const float*)d_in[22];
  const float* mlp_b2   = (const float*)d_in[23];
  const float* mlp_w3   = (const float*)d_in[24];
  const float* mlp_b3   = (const float*)d_in[25];
  const float* log_std  = (const float*)d_in[26];
  char* ws = (char*)d_ws;
  float* out = (float*)d_out;

  // allow >64KB dynamic LDS for k_edge (host-side, idempotent, capture-safe)
  hipFuncSetAttribute((const void*)k_edge,
                      hipFuncAttributeMaxDynamicSharedMemorySize, L_TOTAL);

  hipLaunchKernelGGL(k_prep, dim3(128), dim3(128), 0, stream,
                     edge_w1, edge_w2, coord_w1, velm_w1, mlp_w1, mlp_w2, embed_w, ws);
  hipLaunchKernelGGL(k_node, dim3(128), dim3(256), 0, stream,
                     obs, embed_b, edge_b1, velm_b1, velm_w2, velm_b2,
                     mlp_b1, mlp_b2, mlp_w3, mlp_b3, ws);
  hipLaunchKernelGGL(k_edge, dim3(1024), dim3(512), L_TOTAL, stream,
                     obs, eps, edge_b2, coord_b1, coord_w2, coord_b2, log_std, ws, out);
}

// Round 15
// 101.393 us; speedup vs baseline: 2.7579x; 1.0090x over previous
//
#include <hip/hip_runtime.h>
#include <hip/hip_bf16.h>

typedef float f32x4 __attribute__((ext_vector_type(4)));
typedef __bf16 bf16x8 __attribute__((ext_vector_type(8)));

#define MFMA(a,b,c) __builtin_amdgcn_mfma_f32_16x16x32_bf16(a,b,c,0,0,0)

// workspace layout (bytes)
#define WS_A_BF   0x000000   // bf16 8192*128  (h@W1a + edge_b1), row-major [node][fi]
#define WS_B_BF   0x200000   // bf16 8192*128  (h@W1b), frag-chunk: [t][f>>3][c][f&7]
#define WS_W2F    0x400000   // bf16 128*128   edge_w2  frag-major [(ks*8+nt)*512+lane*8+j]
#define WS_C1F    0x408000   // bf16 128*128   coord_w1 frag-major (contiguous after W2F)
#define WS_W1AT   0x410000   // bf16 128*128   edge_w1[0:128]^T   [out][in]
#define WS_W1BT   0x418000   // bf16 128*128   edge_w1[128:256]^T [out][in]
#define WS_VW1T   0x420000   // bf16 128*128   velm_w1^T
#define WS_MW2T   0x428000   // bf16 128*128   mlp_w2^T
#define WS_EWT    0x430000   // bf16 128*32    embed_w^T (K padded 30->32)
#define WS_MW1T   0x432000   // bf16 128*64    mlp_w1^T  (K padded 34->64)
#define WS_W1S    0x436000   // bf16 128       edge_w1 row256+row257
#define WS_BASE   0x436200   // f32 8192*2     vel_scale*vel + zMLP

// k_edge dynamic-LDS layout (bytes) — 68.25 KB -> 2 blocks/CU (16 waves)
#define L_WGT   0        // 65536: W2F(32K) + C1F(32K), frag-major
#define L_ASH   65536    // 2048:  this block's 8 A-rows (8 x 128 bf16)
#define L_LOC   67584    // 512:   loc f32[128]
#define L_B2    68096    // 512
#define L_CB1   68608    // 512
#define L_C2    69120    // 512
#define L_WSS   69632    // 256:   w1s bf16[128]
#define L_TOTAL 69888

// fast silu: v_exp + v_rcp
static __device__ __forceinline__ float silu_f(float x) {
  float e = __expf(-x);
  return x * __builtin_amdgcn_rcpf(1.0f + e);
}

// packed f32x2 -> bf16x2 in one VALU op
static __device__ __forceinline__ unsigned cvt_pk_bf16(float lo, float hi) {
  unsigned r;
  asm("v_cvt_pk_bf16_f32 %0, %1, %2" : "=v"(r) : "v"(lo), "v"(hi));
  return r;
}

// ---------------- kernel 0: weight prep --------------------------------------
__global__ void k_prep(const float* __restrict__ ew1, const float* __restrict__ ew2,
                       const float* __restrict__ cw1, const float* __restrict__ vw1,
                       const float* __restrict__ mw1, const float* __restrict__ mw2,
                       const float* __restrict__ embw, char* __restrict__ ws) {
  int n = blockIdx.x;   // fo 0..127
  int k = threadIdx.x;  // fi 0..127
  // frag-major index: one 16x32 fragment = 512 elements (64 lanes x 8)
  int ks = k >> 5, lgrp = (k >> 3) & 3, j = k & 7, nt = n >> 4, lid = n & 15;
  int fidx = (ks*8 + nt)*512 + (lgrp*16 + lid)*8 + j;
  ((__bf16*)(ws+WS_W2F))[fidx] = (__bf16)ew2[k*128+n];
  ((__bf16*)(ws+WS_C1F))[fidx] = (__bf16)cw1[k*128+n];
  ((__bf16*)(ws+WS_W1AT))[n*128+k] = (__bf16)ew1[k*128+n];
  ((__bf16*)(ws+WS_W1BT))[n*128+k] = (__bf16)ew1[(128+k)*128+n];
  ((__bf16*)(ws+WS_VW1T))[n*128+k] = (__bf16)vw1[k*128+n];
  ((__bf16*)(ws+WS_MW2T))[n*128+k] = (__bf16)mw2[k*128+n];
  if (k < 32) ((__bf16*)(ws+WS_EWT ))[n*32+k] = (k<30) ? (__bf16)embw[k*128+n] : (__bf16)0.0f;
  if (k < 64) ((__bf16*)(ws+WS_MW1T))[n*64+k] = (k<34) ? (__bf16)mw1[k*128+n] : (__bf16)0.0f;
  if (n == 0) ((__bf16*)(ws+WS_W1S))[k] = (__bf16)(ew1[256*128+k] + ew1[257*128+k]);
}

// ---------------- kernel 1: node-level (h, A_pre, B_pre, vel_scale, zMLP) -----
// 512 blocks x 64 threads (ONE wave = 16 nodes per block): 4x the parallelism
// of the old 128x256 config (which left half the GPU idle on this
// latency-bound kernel). Per-wave code identical.
__global__ __launch_bounds__(64) void k_node(
    const float* __restrict__ obs,
    const float* __restrict__ emb_b,   const float* __restrict__ edge_b1,
    const float* __restrict__ velm_b1, const float* __restrict__ velm_w2,
    const float* __restrict__ velm_b2, const float* __restrict__ mlp_b1,
    const float* __restrict__ mlp_b2,  const float* __restrict__ mlp_w3,
    const float* __restrict__ mlp_b3,  char* __restrict__ ws) {
  __shared__ char hw[4096];          // 16 rows x 256B (one wave)
  const int lane = threadIdx.x;
  const int lgrp = lane>>4, lid = lane&15;
  const int nb = blockIdx.x*16;
  const int node = nb + lid;

  const __bf16* EWT  = (const __bf16*)(ws+WS_EWT);
  const __bf16* W1AT = (const __bf16*)(ws+WS_W1AT);
  const __bf16* W1BT = (const __bf16*)(ws+WS_W1BT);
  const __bf16* VW1T = (const __bf16*)(ws+WS_VW1T);
  const __bf16* MW1T = (const __bf16*)(ws+WS_MW1T);
  const __bf16* MW2T = (const __bf16*)(ws+WS_MW2T);
  __bf16* A_bf = (__bf16*)(ws+WS_A_BF);
  __bf16* B_bf = (__bf16*)(ws+WS_B_BF);
  float* baseo = (float*)(ws+WS_BASE);

  f32x4 acc[8];

  // ---- stage 1: h = h_in @ embed_w + emb_b (K=32 padded) ----
  bf16x8 aobs;
  #pragma unroll
  for (int j = 0; j < 8; ++j) {
    int k = lgrp*8 + j;
    aobs[j] = (k < 30) ? (__bf16)obs[node*34 + 4 + k] : (__bf16)0.0f;
  }
  #pragma unroll
  for (int nt = 0; nt < 8; ++nt) acc[nt] = (f32x4){0.f,0.f,0.f,0.f};
  #pragma unroll
  for (int nt = 0; nt < 8; ++nt) {
    bf16x8 bw = *(const bf16x8*)(EWT + (nt*16+lid)*32 + lgrp*8);
    acc[nt] = MFMA(aobs, bw, acc[nt]);
  }
  #pragma unroll
  for (int nt = 0; nt < 8; ++nt) {
    int col = nt*16 + lid;
    #pragma unroll
    for (int e = 0; e < 4; ++e) {
      int rl = lgrp*4 + e;
      *(__bf16*)(hw + rl*256 + ((col*2) ^ ((rl&7)<<4))) = (__bf16)(acc[nt][e] + emb_b[col]);
    }
  }
  bf16x8 ah[4];
  #pragma unroll
  for (int ks = 0; ks < 4; ++ks)
    ah[ks] = *(const bf16x8*)(hw + lid*256 + ((ks*64 + lgrp*16) ^ ((lid&7)<<4)));

  // ---- stage 2: A_pre = h @ W1a + edge_b1 -> ws (bf16, row-major) ----
  #pragma unroll
  for (int nt = 0; nt < 8; ++nt) acc[nt] = (f32x4){0.f,0.f,0.f,0.f};
  #pragma unroll
  for (int ks = 0; ks < 4; ++ks)
    #pragma unroll
    for (int nt = 0; nt < 8; ++nt) {
      bf16x8 bw = *(const bf16x8*)(W1AT + (nt*16+lid)*128 + ks*32 + lgrp*8);
      acc[nt] = MFMA(ah[ks], bw, acc[nt]);
    }
  #pragma unroll
  for (int nt = 0; nt < 8; ++nt) {
    int col = nt*16 + lid;
    #pragma unroll
    for (int e = 0; e < 4; ++e)
      A_bf[(nb + lgrp*4 + e)*128 + col] = (__bf16)(acc[nt][e] + edge_b1[col]);
  }

  // ---- stage 3: B_pre = h @ W1b -> ws (bf16, frag-chunk layout) ----
  #pragma unroll
  for (int nt = 0; nt < 8; ++nt) acc[nt] = (f32x4){0.f,0.f,0.f,0.f};
  #pragma unroll
  for (int ks = 0; ks < 4; ++ks)
    #pragma unroll
    for (int nt = 0; nt < 8; ++nt) {
      bf16x8 bw = *(const bf16x8*)(W1BT + (nt*16+lid)*128 + ks*32 + lgrp*8);
      acc[nt] = MFMA(ah[ks], bw, acc[nt]);
    }
  {
    const int t = blockIdx.x >> 2;      // 4 blocks per t (16 nodes each)
    const int wq = blockIdx.x & 3;      // position within the t's 64 nodes
    #pragma unroll
    for (int nt = 0; nt < 8; ++nt) {
      int chunk = nt*2 + (lid>>3), j = lid & 7;
      #pragma unroll
      for (int e = 0; e < 4; ++e) {
        int c = wq*16 + lgrp*4 + e;
        B_bf[(size_t)t*8192 + chunk*512 + c*8 + j] = (__bf16)acc[nt][e];
      }
    }
  }

  // ---- stage 4: vel_scale = silu(h@velm_w1 + b1) @ velm_w2 + b2 ----
  #pragma unroll
  for (int nt = 0; nt < 8; ++nt) acc[nt] = (f32x4){0.f,0.f,0.f,0.f};
  #pragma unroll
  for (int ks = 0; ks < 4; ++ks)
    #pragma unroll
    for (int nt = 0; nt < 8; ++nt) {
      bf16x8 bw = *(const bf16x8*)(VW1T + (nt*16+lid)*128 + ks*32 + lgrp*8);
      acc[nt] = MFMA(ah[ks], bw, acc[nt]);
    }
  float pv[4] = {0.f,0.f,0.f,0.f};
  #pragma unroll
  for (int nt = 0; nt < 8; ++nt) {
    int col = nt*16 + lid;
    float w2 = velm_w2[col], b = velm_b1[col];
    #pragma unroll
    for (int e = 0; e < 4; ++e) pv[e] += silu_f(acc[nt][e] + b) * w2;
  }
  #pragma unroll
  for (int d = 1; d < 16; d <<= 1) {
    #pragma unroll
    for (int e = 0; e < 4; ++e) pv[e] += __shfl_xor(pv[e], d, 64);
  }
  float vs[4];
  #pragma unroll
  for (int e = 0; e < 4; ++e) vs[e] = pv[e] + velm_b2[0];

  // ---- stage 5: z1 = silu(obs @ mlp_w1 + b1) (K=64 padded) ----
  bf16x8 az[2];
  #pragma unroll
  for (int ks2 = 0; ks2 < 2; ++ks2)
    #pragma unroll
    for (int j = 0; j < 8; ++j) {
      int k = ks2*32 + lgrp*8 + j;
      az[ks2][j] = (k < 34) ? (__bf16)obs[node*34 + k] : (__bf16)0.0f;
    }
  #pragma unroll
  for (int nt = 0; nt < 8; ++nt) acc[nt] = (f32x4){0.f,0.f,0.f,0.f};
  #pragma unroll
  for (int ks2 = 0; ks2 < 2; ++ks2)
    #pragma unroll
    for (int nt = 0; nt < 8; ++nt) {
      bf16x8 bw = *(const bf16x8*)(MW1T + (nt*16+lid)*64 + ks2*32 + lgrp*8);
      acc[nt] = MFMA(az[ks2], bw, acc[nt]);
    }
  #pragma unroll
  for (int nt = 0; nt < 8; ++nt) {
    int col = nt*16 + lid;
    float b = mlp_b1[col];
    #pragma unroll
    for (int e = 0; e < 4; ++e) {
      int rl = lgrp*4 + e;
      *(__bf16*)(hw + rl*256 + ((col*2) ^ ((rl&7)<<4))) = (__bf16)silu_f(acc[nt][e] + b);
    }
  }
  bf16x8 az1[4];
  #pragma unroll
  for (int ks = 0; ks < 4; ++ks)
    az1[ks] = *(const bf16x8*)(hw + lid*256 + ((ks*64 + lgrp*16) ^ ((lid&7)<<4)));

  // ---- stage 6: z2 = silu(z1@mlp_w2 + b2); o = z2@mlp_w3 ----
  #pragma unroll
  for (int nt = 0; nt < 8; ++nt) acc[nt] = (f32x4){0.f,0.f,0.f,0.f};
  #pragma unroll
  for (int ks = 0; ks < 4; ++ks)
    #pragma unroll
    for (int nt = 0; nt < 8; ++nt) {
      bf16x8 bw = *(const bf16x8*)(MW2T + (nt*16+lid)*128 + ks*32 + lgrp*8);
      acc[nt] = MFMA(az1[ks], bw, acc[nt]);
    }
  float p0[4] = {0.f,0.f,0.f,0.f}, p1[4] = {0.f,0.f,0.f,0.f};
  #pragma unroll
  for (int nt = 0; nt < 8; ++nt) {
    int col = nt*16 + lid;
    float b = mlp_b2[col], w0 = mlp_w3[col*2], w1 = mlp_w3[col*2+1];
    #pragma unroll
    for (int e = 0; e < 4; ++e) {
      float z2 = silu_f(acc[nt][e] + b);
      p0[e] += z2*w0; p1[e] += z2*w1;
    }
  }
  #pragma unroll
  for (int d = 1; d < 16; d <<= 1) {
    #pragma unroll
    for (int e = 0; e < 4; ++e) { p0[e] += __shfl_xor(p0[e], d, 64); p1[e] += __shfl_xor(p1[e], d, 64); }
  }

  // ---- stage 7: base = vel_scale*vel + zMLP out ----
  if (lid == 0) {
    #pragma unroll
    for (int e = 0; e < 4; ++e) {
      int row = nb + lgrp*4 + e;
      float v0 = obs[row*34+2], v1 = obs[row*34+3];
      baseo[row*2+0] = vs[e]*v0 + p0[e] + mlp_b3[0];
      baseo[row*2+1] = vs[e]*v1 + p1[e] + mlp_b3[1];
    }
  }
}

// ---------------- kernel 2: edge chain + aggregation + output -----------------
// 1024 blocks x 512 threads (8 waves, one r per wave). R14 structure; ONE
// change: GEMM1 ks loop unroll-2 (bounded: ~105 regs < 128 cap) for in-wave
// ILP — two {ds_read + global bv + silu + MFMA} batches in flight.
__global__ __launch_bounds__(512, 4) void k_edge(
    const float* __restrict__ obs, const float* __restrict__ eps,
    const float* __restrict__ edge_b2, const float* __restrict__ coord_b1,
    const float* __restrict__ coord_w2, const float* __restrict__ coord_b2,
    const float* __restrict__ log_std,
    const char* __restrict__ ws, float* __restrict__ out) {
  extern __shared__ __align__(16) char lds[];
  const int tid = threadIdx.x;
  const int wid = tid>>6, lane = tid&63, lgrp = lane>>4, lid = lane&15;
  const int t = blockIdx.x >> 3, rgrp = blockIdx.x & 7;
  const int rl = rgrp*8 + wid;
  const int r  = t*64 + rl;
  float* locsh = (float*)(lds + L_LOC);
  float* b2sh  = (float*)(lds + L_B2);
  float* cb1sh = (float*)(lds + L_CB1);
  float* c2sh  = (float*)(lds + L_C2);

  const __bf16* A_bf = (const __bf16*)(ws+WS_A_BF);
  const __bf16* Bt   = (const __bf16*)(ws+WS_B_BF) + (size_t)t*8192;
  const float* baseo = (const float*)(ws+WS_BASE);

  // ---- stage weights (64KB) + A-rows (2KB) + consts; single barrier ----
  {
    const uint4* gw = (const uint4*)(ws+WS_W2F);
    uint4* lw = (uint4*)(lds + L_WGT);
    #pragma unroll
    for (int i = 0; i < 8; ++i) lw[tid + i*512] = gw[tid + i*512];
    if (tid < 128) {
      int row = tid >> 4, e16 = tid & 15;
      *(uint4*)(lds + L_ASH + row*256 + e16*16) =
          *(const uint4*)(A_bf + (size_t)(t*64 + rgrp*8 + row)*128 + e16*8);
      locsh[tid] = obs[(size_t)(t*64 + (tid>>1))*34 + (tid&1)];
      b2sh[tid]  = edge_b2[tid];
      cb1sh[tid] = coord_b1[tid];
      c2sh[tid]  = coord_w2[tid];
      ((unsigned short*)(lds+L_WSS))[tid] = ((const unsigned short*)(ws+WS_W1S))[tid];
    }
  }
  __syncthreads();

  const char* W2s = lds + L_WGT;           // 32 frags x 1KB
  const char* C1s = lds + L_WGT + 32768;
  const char* ash = lds + L_ASH + wid*256; // this wave's A-row (128 bf16)
  const char* wss = lds + L_WSS;

  const float cb2 = coord_b2[0];
  const float lr0 = locsh[rl*2], lr1 = locsh[rl*2+1];
  // bpermute byte-addresses: src_lane = (lgrp&1)*32 + cgrp*16 + lid
  const int adr0 = (((lgrp&1)<<5) + lid) << 2;
  const int adr1 = adr0 + (16<<2);

  float agg0 = 0.f, agg1 = 0.f;

  #pragma unroll 1
  for (int ct = 0; ct < 4; ++ct) {
    const int c = ct*16 + lid;          // this lane's edge (B-frag col)
    const float d0 = lr0 - locsh[c*2], d1 = lr1 - locsh[c*2+1];
    const float rad = d0*d0 + d1*d1;

    // single accumulator array reused by both GEMMs (32 AGPR total)
    f32x4 acc[8];

    // ---- GEMM1: m2^T, C-init = edge_b2; unroll-2 (ILP, bounded live set) ----
    #pragma unroll
    for (int nt = 0; nt < 8; ++nt)
      acc[nt] = *(const f32x4*)(b2sh + nt*16 + lgrp*4);
    #pragma unroll 2
    for (int ks = 0; ks < 4; ++ks) {
      bf16x8 aAk = *(const bf16x8*)(ash + ks*64 + lgrp*16);
      bf16x8 wsv = *(const bf16x8*)(wss + ks*64 + lgrp*16);
      bf16x8 bv  = *(const bf16x8*)(Bt + (ks*4+lgrp)*512 + c*8);
      bf16x8 a1;
      #pragma unroll
      for (int j = 0; j < 8; ++j) {
        float f = (float)aAk[j] + (float)bv[j] + rad*(float)wsv[j];
        a1[j] = (__bf16)silu_f(f);
      }
      #pragma unroll
      for (int nt = 0; nt < 8; ++nt) {
        bf16x8 bw = *(const bf16x8*)(W2s + ((ks*8+nt)*512 + lane*8)*2);
        acc[nt] = MFMA(bw, a1, acc[nt]);
      }
    }

    // ---- silu(m2) + pack to bf16x2 words (acc dead afterwards) ----
    unsigned pk[8][2];
    #pragma unroll
    for (int nt = 0; nt < 8; ++nt) {
      float s0 = silu_f(acc[nt][0]), s1 = silu_f(acc[nt][1]);
      float s2 = silu_f(acc[nt][2]), s3 = silu_f(acc[nt][3]);
      pk[nt][0] = cvt_pk_bf16(s0, s1);
      pk[nt][1] = cvt_pk_bf16(s2, s3);
    }

    // ---- GEMM2: tc^T, C-init = coord_b1; a2 gathered via bpermute ----
    #pragma unroll
    for (int nt = 0; nt < 8; ++nt)
      acc[nt] = *(const f32x4*)(cb1sh + nt*16 + lgrp*4);
    #pragma unroll    // FULL unroll: pk[] indices must be compile-time (scratch rule)
    for (int ks2 = 0; ks2 < 4; ++ks2) {
      unsigned g[4];
      #pragma unroll
      for (int cg = 0; cg < 2; ++cg)
        #pragma unroll
        for (int p = 0; p < 2; ++p) {
          int a = cg ? adr1 : adr0;
          unsigned vlo = (unsigned)__builtin_amdgcn_ds_bpermute(a, (int)pk[2*ks2][p]);
          unsigned vhi = (unsigned)__builtin_amdgcn_ds_bpermute(a, (int)pk[2*ks2+1][p]);
          g[cg*2+p] = (lgrp < 2) ? vlo : vhi;
        }
      union { unsigned u[4]; bf16x8 v; } cvt;
      cvt.u[0] = g[0]; cvt.u[1] = g[1]; cvt.u[2] = g[2]; cvt.u[3] = g[3];
      bf16x8 a2 = cvt.v;
      #pragma unroll
      for (int nt = 0; nt < 8; ++nt) {
        bf16x8 bw = *(const bf16x8*)(C1s + ((ks2*8+nt)*512 + lane*8)*2);
        acc[nt] = MFMA(bw, a2, acc[nt]);
      }
    }

    // ---- epilogue: cw = silu(tc^T)·c2 summed over rows; rows split by lgrp ----
    float pcw = 0.f;
    #pragma unroll
    for (int nt = 0; nt < 8; ++nt) {
      f32x4 c2v = *(const f32x4*)(c2sh + nt*16 + lgrp*4);
      #pragma unroll
      for (int e = 0; e < 4; ++e)
        pcw += silu_f(acc[nt][e]) * c2v[e];
    }
    pcw += __shfl_xor(pcw, 16, 64);
    pcw += __shfl_xor(pcw, 32, 64);
    float cw = pcw + cb2;
    float s = cw * __builtin_amdgcn_rcpf(__builtin_amdgcn_sqrtf(rad) + 1.0f);
    agg0 += d0*s; agg1 += d1*s;
  }

  // each 16-lane group independently holds all-64-edge partials (edge=lid per ct)
  agg0 += __shfl_xor(agg0, 1, 64); agg1 += __shfl_xor(agg1, 1, 64);
  agg0 += __shfl_xor(agg0, 2, 64); agg1 += __shfl_xor(agg1, 2, 64);
  agg0 += __shfl_xor(agg0, 4, 64); agg1 += __shfl_xor(agg1, 4, 64);
  agg0 += __shfl_xor(agg0, 8, 64); agg1 += __shfl_xor(agg1, 8, 64);

  if (lane == 0) {
    float mu0 = baseo[r*2+0] + agg0;
    float mu1 = baseo[r*2+1] + agg1;
    float ls0 = log_std[0], ls1 = log_std[1];
    float e0 = eps[r*2+0], e1 = eps[r*2+1];
    const float C = 0.9189385332046727f; // 0.5*log(2*pi)
    out[r*4+0] = mu0 + __expf(ls0)*e0;
    out[r*4+1] = mu1 + __expf(ls1)*e1;
    out[r*4+2] = -0.5f*e0*e0 - ls0 - C;
    out[r*4+3] = -0.5f*e1*e1 - ls1 - C;
  }
}

extern "C" void kernel_launch(void* const* d_in, const int* in_sizes, int n_in,
                              void* d_out, int out_size, void* d_ws, size_t ws_size,
                              hipStream_t stream) {
  const float* obs      = (const float*)d_in[0];
  const float* eps      = (const float*)d_in[1];
  const float* embed_w  = (const float*)d_in[2];
  const float* embed_b  = (const float*)d_in[3];
  const float* edge_w1  = (const float*)d_in[4];
  const float* edge_b1  = (const float*)d_in[5];
  const float* edge_w2  = (const float*)d_in[6];
  const float* edge_b2  = (const float*)d_in[7];
  const float* coord_w1 = (const float*)d_in[8];
  const float* coord_b1 = (const float*)d_in[9];
  const float* coord_w2 = (const float*)d_in[10];
  const float* coord_b2 = (const float*)d_in[11];
  const float* velm_w1  = (const float*)d_in[12];
  const float* velm_b1  = (const float*)d_in[13];
  const float* velm_w2  = (const float*)d_in[14];
  const float* velm_b2  = (const float*)d_in[15];
  const float* mlp_w1   = (const float*)d_in[20];
  const float* mlp_b1   = (const float*)d_in[21];
  const float* mlp_w2   = (const float*)d_in[22];
  const float* mlp_b2   = (const float*)d_in[23];
  const float* mlp_w3   = (const float*)d_in[24];
  const float* mlp_b3   = (const float*)d_in[25];
  const float* log_std  = (const float*)d_in[26];
  char* ws = (char*)d_ws;
  float* out = (float*)d_out;

  // allow >64KB dynamic LDS for k_edge (host-side, idempotent, capture-safe)
  hipFuncSetAttribute((const void*)k_edge,
                      hipFuncAttributeMaxDynamicSharedMemorySize, L_TOTAL);

  hipLaunchKernelGGL(k_prep, dim3(128), dim3(128), 0, stream,
                     edge_w1, edge_w2, coord_w1, velm_w1, mlp_w1, mlp_w2, embed_w, ws);
  hipLaunchKernelGGL(k_node, dim3(512), dim3(64), 0, stream,
                     obs, embed_b, edge_b1, velm_b1, velm_w2, velm_b2,
                     mlp_b1, mlp_b2, mlp_w3, mlp_b3, ws);
  hipLaunchKernelGGL(k_edge, dim3(1024), dim3(512), L_TOTAL, stream,
                     obs, eps, edge_b2, coord_b1, coord_w2, coord_b2, log_std, ws, out);
}

// Round 16
// 96.747 us; speedup vs baseline: 2.8903x; 1.0480x over previous
//
#include <hip/hip_runtime.h>
#include <hip/hip_bf16.h>

typedef float f32x4 __attribute__((ext_vector_type(4)));
typedef __bf16 bf16x8 __attribute__((ext_vector_type(8)));

#define MFMA(a,b,c) __builtin_amdgcn_mfma_f32_16x16x32_bf16(a,b,c,0,0,0)

// workspace layout (bytes)
#define WS_A_BF   0x000000   // bf16 8192*128  (h@W1a + edge_b1), row-major [node][fi]
#define WS_B_BF   0x200000   // bf16 8192*128  (h@W1b), frag-chunk: [t][f>>3][c][f&7]
#define WS_W2F    0x400000   // bf16 128*128   edge_w2  frag-major [(ks*8+nt)*512+lane*8+j]
#define WS_C1F    0x408000   // bf16 128*128   coord_w1 frag-major (contiguous after W2F)
#define WS_W1AT   0x410000   // bf16 128*128   edge_w1[0:128]^T   [out][in]
#define WS_W1BT   0x418000   // bf16 128*128   edge_w1[128:256]^T [out][in]
#define WS_VW1T   0x420000   // bf16 128*128   velm_w1^T
#define WS_MW2T   0x428000   // bf16 128*128   mlp_w2^T
#define WS_EWT    0x430000   // bf16 128*32    embed_w^T (K padded 30->32)
#define WS_MW1T   0x432000   // bf16 128*64    mlp_w1^T  (K padded 34->64)
#define WS_W1S    0x436000   // bf16 128       edge_w1 row256+row257
#define WS_BASE   0x436200   // f32 8192*2     vel_scale*vel + zMLP

// k_edge dynamic-LDS layout (bytes) — 68.25 KB -> 2 blocks/CU (16 waves)
#define L_WGT   0        // 65536: W2F(32K) + C1F(32K), frag-major
#define L_ASH   65536    // 2048:  this block's 8 A-rows (8 x 128 bf16)
#define L_LOC   67584    // 512:   loc f32[128]
#define L_B2    68096    // 512
#define L_CB1   68608    // 512
#define L_C2    69120    // 512
#define L_WSS   69632    // 256:   w1s bf16[128]
#define L_TOTAL 69888

// fast silu: v_exp + v_rcp
static __device__ __forceinline__ float silu_f(float x) {
  float e = __expf(-x);
  return x * __builtin_amdgcn_rcpf(1.0f + e);
}

// packed f32x2 -> bf16x2 in one VALU op
static __device__ __forceinline__ unsigned cvt_pk_bf16(float lo, float hi) {
  unsigned r;
  asm("v_cvt_pk_bf16_f32 %0, %1, %2" : "=v"(r) : "v"(lo), "v"(hi));
  return r;
}

// ---------------- kernel 0: weight prep --------------------------------------
__global__ void k_prep(const float* __restrict__ ew1, const float* __restrict__ ew2,
                       const float* __restrict__ cw1, const float* __restrict__ vw1,
                       const float* __restrict__ mw1, const float* __restrict__ mw2,
                       const float* __restrict__ embw, char* __restrict__ ws) {
  int n = blockIdx.x;   // fo 0..127
  int k = threadIdx.x;  // fi 0..127
  // frag-major index: one 16x32 fragment = 512 elements (64 lanes x 8)
  int ks = k >> 5, lgrp = (k >> 3) & 3, j = k & 7, nt = n >> 4, lid = n & 15;
  int fidx = (ks*8 + nt)*512 + (lgrp*16 + lid)*8 + j;
  ((__bf16*)(ws+WS_W2F))[fidx] = (__bf16)ew2[k*128+n];
  ((__bf16*)(ws+WS_C1F))[fidx] = (__bf16)cw1[k*128+n];
  ((__bf16*)(ws+WS_W1AT))[n*128+k] = (__bf16)ew1[k*128+n];
  ((__bf16*)(ws+WS_W1BT))[n*128+k] = (__bf16)ew1[(128+k)*128+n];
  ((__bf16*)(ws+WS_VW1T))[n*128+k] = (__bf16)vw1[k*128+n];
  ((__bf16*)(ws+WS_MW2T))[n*128+k] = (__bf16)mw2[k*128+n];
  if (k < 32) ((__bf16*)(ws+WS_EWT ))[n*32+k] = (k<30) ? (__bf16)embw[k*128+n] : (__bf16)0.0f;
  if (k < 64) ((__bf16*)(ws+WS_MW1T))[n*64+k] = (k<34) ? (__bf16)mw1[k*128+n] : (__bf16)0.0f;
  if (n == 0) ((__bf16*)(ws+WS_W1S))[k] = (__bf16)(ew1[256*128+k] + ew1[257*128+k]);
}

// ---------------- kernel 1: node-level (h, A_pre, B_pre, vel_scale, zMLP) -----
// 512 blocks x 64 threads (ONE wave = 16 nodes per block): 4x the parallelism
// of the old 128x256 config. Per-wave code identical.
__global__ __launch_bounds__(64) void k_node(
    const float* __restrict__ obs,
    const float* __restrict__ emb_b,   const float* __restrict__ edge_b1,
    const float* __restrict__ velm_b1, const float* __restrict__ velm_w2,
    const float* __restrict__ velm_b2, const float* __restrict__ mlp_b1,
    const float* __restrict__ mlp_b2,  const float* __restrict__ mlp_w3,
    const float* __restrict__ mlp_b3,  char* __restrict__ ws) {
  __shared__ char hw[4096];          // 16 rows x 256B (one wave)
  const int lane = threadIdx.x;
  const int lgrp = lane>>4, lid = lane&15;
  const int nb = blockIdx.x*16;
  const int node = nb + lid;

  const __bf16* EWT  = (const __bf16*)(ws+WS_EWT);
  const __bf16* W1AT = (const __bf16*)(ws+WS_W1AT);
  const __bf16* W1BT = (const __bf16*)(ws+WS_W1BT);
  const __bf16* VW1T = (const __bf16*)(ws+WS_VW1T);
  const __bf16* MW1T = (const __bf16*)(ws+WS_MW1T);
  const __bf16* MW2T = (const __bf16*)(ws+WS_MW2T);
  __bf16* A_bf = (__bf16*)(ws+WS_A_BF);
  __bf16* B_bf = (__bf16*)(ws+WS_B_BF);
  float* baseo = (float*)(ws+WS_BASE);

  f32x4 acc[8];

  // ---- stage 1: h = h_in @ embed_w + emb_b (K=32 padded) ----
  bf16x8 aobs;
  #pragma unroll
  for (int j = 0; j < 8; ++j) {
    int k = lgrp*8 + j;
    aobs[j] = (k < 30) ? (__bf16)obs[node*34 + 4 + k] : (__bf16)0.0f;
  }
  #pragma unroll
  for (int nt = 0; nt < 8; ++nt) acc[nt] = (f32x4){0.f,0.f,0.f,0.f};
  #pragma unroll
  for (int nt = 0; nt < 8; ++nt) {
    bf16x8 bw = *(const bf16x8*)(EWT + (nt*16+lid)*32 + lgrp*8);
    acc[nt] = MFMA(aobs, bw, acc[nt]);
  }
  #pragma unroll
  for (int nt = 0; nt < 8; ++nt) {
    int col = nt*16 + lid;
    #pragma unroll
    for (int e = 0; e < 4; ++e) {
      int rl = lgrp*4 + e;
      *(__bf16*)(hw + rl*256 + ((col*2) ^ ((rl&7)<<4))) = (__bf16)(acc[nt][e] + emb_b[col]);
    }
  }
  bf16x8 ah[4];
  #pragma unroll
  for (int ks = 0; ks < 4; ++ks)
    ah[ks] = *(const bf16x8*)(hw + lid*256 + ((ks*64 + lgrp*16) ^ ((lid&7)<<4)));

  // ---- stage 2: A_pre = h @ W1a + edge_b1 -> ws (bf16, row-major) ----
  #pragma unroll
  for (int nt = 0; nt < 8; ++nt) acc[nt] = (f32x4){0.f,0.f,0.f,0.f};
  #pragma unroll
  for (int ks = 0; ks < 4; ++ks)
    #pragma unroll
    for (int nt = 0; nt < 8; ++nt) {
      bf16x8 bw = *(const bf16x8*)(W1AT + (nt*16+lid)*128 + ks*32 + lgrp*8);
      acc[nt] = MFMA(ah[ks], bw, acc[nt]);
    }
  #pragma unroll
  for (int nt = 0; nt < 8; ++nt) {
    int col = nt*16 + lid;
    #pragma unroll
    for (int e = 0; e < 4; ++e)
      A_bf[(nb + lgrp*4 + e)*128 + col] = (__bf16)(acc[nt][e] + edge_b1[col]);
  }

  // ---- stage 3: B_pre = h @ W1b -> ws (bf16, frag-chunk layout) ----
  #pragma unroll
  for (int nt = 0; nt < 8; ++nt) acc[nt] = (f32x4){0.f,0.f,0.f,0.f};
  #pragma unroll
  for (int ks = 0; ks < 4; ++ks)
    #pragma unroll
    for (int nt = 0; nt < 8; ++nt) {
      bf16x8 bw = *(const bf16x8*)(W1BT + (nt*16+lid)*128 + ks*32 + lgrp*8);
      acc[nt] = MFMA(ah[ks], bw, acc[nt]);
    }
  {
    const int t = blockIdx.x >> 2;      // 4 blocks per t (16 nodes each)
    const int wq = blockIdx.x & 3;      // position within the t's 64 nodes
    #pragma unroll
    for (int nt = 0; nt < 8; ++nt) {
      int chunk = nt*2 + (lid>>3), j = lid & 7;
      #pragma unroll
      for (int e = 0; e < 4; ++e) {
        int c = wq*16 + lgrp*4 + e;
        B_bf[(size_t)t*8192 + chunk*512 + c*8 + j] = (__bf16)acc[nt][e];
      }
    }
  }

  // ---- stage 4: vel_scale = silu(h@velm_w1 + b1) @ velm_w2 + b2 ----
  #pragma unroll
  for (int nt = 0; nt < 8; ++nt) acc[nt] = (f32x4){0.f,0.f,0.f,0.f};
  #pragma unroll
  for (int ks = 0; ks < 4; ++ks)
    #pragma unroll
    for (int nt = 0; nt < 8; ++nt) {
      bf16x8 bw = *(const bf16x8*)(VW1T + (nt*16+lid)*128 + ks*32 + lgrp*8);
      acc[nt] = MFMA(ah[ks], bw, acc[nt]);
    }
  float pv[4] = {0.f,0.f,0.f,0.f};
  #pragma unroll
  for (int nt = 0; nt < 8; ++nt) {
    int col = nt*16 + lid;
    float w2 = velm_w2[col], b = velm_b1[col];
    #pragma unroll
    for (int e = 0; e < 4; ++e) pv[e] += silu_f(acc[nt][e] + b) * w2;
  }
  #pragma unroll
  for (int d = 1; d < 16; d <<= 1) {
    #pragma unroll
    for (int e = 0; e < 4; ++e) pv[e] += __shfl_xor(pv[e], d, 64);
  }
  float vs[4];
  #pragma unroll
  for (int e = 0; e < 4; ++e) vs[e] = pv[e] + velm_b2[0];

  // ---- stage 5: z1 = silu(obs @ mlp_w1 + b1) (K=64 padded) ----
  bf16x8 az[2];
  #pragma unroll
  for (int ks2 = 0; ks2 < 2; ++ks2)
    #pragma unroll
    for (int j = 0; j < 8; ++j) {
      int k = ks2*32 + lgrp*8 + j;
      az[ks2][j] = (k < 34) ? (__bf16)obs[node*34 + k] : (__bf16)0.0f;
    }
  #pragma unroll
  for (int nt = 0; nt < 8; ++nt) acc[nt] = (f32x4){0.f,0.f,0.f,0.f};
  #pragma unroll
  for (int ks2 = 0; ks2 < 2; ++ks2)
    #pragma unroll
    for (int nt = 0; nt < 8; ++nt) {
      bf16x8 bw = *(const bf16x8*)(MW1T + (nt*16+lid)*64 + ks2*32 + lgrp*8);
      acc[nt] = MFMA(az[ks2], bw, acc[nt]);
    }
  #pragma unroll
  for (int nt = 0; nt < 8; ++nt) {
    int col = nt*16 + lid;
    float b = mlp_b1[col];
    #pragma unroll
    for (int e = 0; e < 4; ++e) {
      int rl = lgrp*4 + e;
      *(__bf16*)(hw + rl*256 + ((col*2) ^ ((rl&7)<<4))) = (__bf16)silu_f(acc[nt][e] + b);
    }
  }
  bf16x8 az1[4];
  #pragma unroll
  for (int ks = 0; ks < 4; ++ks)
    az1[ks] = *(const bf16x8*)(hw + lid*256 + ((ks*64 + lgrp*16) ^ ((lid&7)<<4)));

  // ---- stage 6: z2 = silu(z1@mlp_w2 + b2); o = z2@mlp_w3 ----
  #pragma unroll
  for (int nt = 0; nt < 8; ++nt) acc[nt] = (f32x4){0.f,0.f,0.f,0.f};
  #pragma unroll
  for (int ks = 0; ks < 4; ++ks)
    #pragma unroll
    for (int nt = 0; nt < 8; ++nt) {
      bf16x8 bw = *(const bf16x8*)(MW2T + (nt*16+lid)*128 + ks*32 + lgrp*8);
      acc[nt] = MFMA(az1[ks], bw, acc[nt]);
    }
  float p0[4] = {0.f,0.f,0.f,0.f}, p1[4] = {0.f,0.f,0.f,0.f};
  #pragma unroll
  for (int nt = 0; nt < 8; ++nt) {
    int col = nt*16 + lid;
    float b = mlp_b2[col], w0 = mlp_w3[col*2], w1 = mlp_w3[col*2+1];
    #pragma unroll
    for (int e = 0; e < 4; ++e) {
      float z2 = silu_f(acc[nt][e] + b);
      p0[e] += z2*w0; p1[e] += z2*w1;
    }
  }
  #pragma unroll
  for (int d = 1; d < 16; d <<= 1) {
    #pragma unroll
    for (int e = 0; e < 4; ++e) { p0[e] += __shfl_xor(p0[e], d, 64); p1[e] += __shfl_xor(p1[e], d, 64); }
  }

  // ---- stage 7: base = vel_scale*vel + zMLP out ----
  if (lid == 0) {
    #pragma unroll
    for (int e = 0; e < 4; ++e) {
      int row = nb + lgrp*4 + e;
      float v0 = obs[row*34+2], v1 = obs[row*34+3];
      baseo[row*2+0] = vs[e]*v0 + p0[e] + mlp_b3[0];
      baseo[row*2+1] = vs[e]*v1 + p1[e] + mlp_b3[1];
    }
  }
}

// ---------------- kernel 2: edge chain + aggregation + output -----------------
// 1024 blocks x 512 threads (8 waves, one r per wave). R14's proven-best
// structure: GEMM1 ks-loop UNROLL-1 (R15's unroll-2 regressed: compiler
// interleave lengthened the silu critical path), A-rows in LDS, bpermute
// transpose, single acc[8], no spill.
__global__ __launch_bounds__(512, 4) void k_edge(
    const float* __restrict__ obs, const float* __restrict__ eps,
    const float* __restrict__ edge_b2, const float* __restrict__ coord_b1,
    const float* __restrict__ coord_w2, const float* __restrict__ coord_b2,
    const float* __restrict__ log_std,
    const char* __restrict__ ws, float* __restrict__ out) {
  extern __shared__ __align__(16) char lds[];
  const int tid = threadIdx.x;
  const int wid = tid>>6, lane = tid&63, lgrp = lane>>4, lid = lane&15;
  const int t = blockIdx.x >> 3, rgrp = blockIdx.x & 7;
  const int rl = rgrp*8 + wid;
  const int r  = t*64 + rl;
  float* locsh = (float*)(lds + L_LOC);
  float* b2sh  = (float*)(lds + L_B2);
  float* cb1sh = (float*)(lds + L_CB1);
  float* c2sh  = (float*)(lds + L_C2);

  const __bf16* A_bf = (const __bf16*)(ws+WS_A_BF);
  const __bf16* Bt   = (const __bf16*)(ws+WS_B_BF) + (size_t)t*8192;
  const float* baseo = (const float*)(ws+WS_BASE);

  // ---- stage weights (64KB) + A-rows (2KB) + consts; single barrier ----
  {
    const uint4* gw = (const uint4*)(ws+WS_W2F);
    uint4* lw = (uint4*)(lds + L_WGT);
    #pragma unroll
    for (int i = 0; i < 8; ++i) lw[tid + i*512] = gw[tid + i*512];
    if (tid < 128) {
      int row = tid >> 4, e16 = tid & 15;
      *(uint4*)(lds + L_ASH + row*256 + e16*16) =
          *(const uint4*)(A_bf + (size_t)(t*64 + rgrp*8 + row)*128 + e16*8);
      locsh[tid] = obs[(size_t)(t*64 + (tid>>1))*34 + (tid&1)];
      b2sh[tid]  = edge_b2[tid];
      cb1sh[tid] = coord_b1[tid];
      c2sh[tid]  = coord_w2[tid];
      ((unsigned short*)(lds+L_WSS))[tid] = ((const unsigned short*)(ws+WS_W1S))[tid];
    }
  }
  __syncthreads();

  const char* W2s = lds + L_WGT;           // 32 frags x 1KB
  const char* C1s = lds + L_WGT + 32768;
  const char* ash = lds + L_ASH + wid*256; // this wave's A-row (128 bf16)
  const char* wss = lds + L_WSS;

  const float cb2 = coord_b2[0];
  const float lr0 = locsh[rl*2], lr1 = locsh[rl*2+1];
  // bpermute byte-addresses: src_lane = (lgrp&1)*32 + cgrp*16 + lid
  const int adr0 = (((lgrp&1)<<5) + lid) << 2;
  const int adr1 = adr0 + (16<<2);

  float agg0 = 0.f, agg1 = 0.f;

  #pragma unroll 1
  for (int ct = 0; ct < 4; ++ct) {
    const int c = ct*16 + lid;          // this lane's edge (B-frag col)
    const float d0 = lr0 - locsh[c*2], d1 = lr1 - locsh[c*2+1];
    const float rad = d0*d0 + d1*d1;

    // single accumulator array reused by both GEMMs (32 AGPR total)
    f32x4 acc[8];

    // ---- GEMM1: m2^T, C-init = edge_b2; unroll-1 (bounded live set) ----
    #pragma unroll
    for (int nt = 0; nt < 8; ++nt)
      acc[nt] = *(const f32x4*)(b2sh + nt*16 + lgrp*4);
    #pragma unroll 1
    for (int ks = 0; ks < 4; ++ks) {
      bf16x8 aAk = *(const bf16x8*)(ash + ks*64 + lgrp*16);
      bf16x8 wsv = *(const bf16x8*)(wss + ks*64 + lgrp*16);
      bf16x8 bv  = *(const bf16x8*)(Bt + (ks*4+lgrp)*512 + c*8);
      bf16x8 a1;
      #pragma unroll
      for (int j = 0; j < 8; ++j) {
        float f = (float)aAk[j] + (float)bv[j] + rad*(float)wsv[j];
        a1[j] = (__bf16)silu_f(f);
      }
      #pragma unroll
      for (int nt = 0; nt < 8; ++nt) {
        bf16x8 bw = *(const bf16x8*)(W2s + ((ks*8+nt)*512 + lane*8)*2);
        acc[nt] = MFMA(bw, a1, acc[nt]);
      }
    }

    // ---- silu(m2) + pack to bf16x2 words (acc dead afterwards) ----
    unsigned pk[8][2];
    #pragma unroll
    for (int nt = 0; nt < 8; ++nt) {
      float s0 = silu_f(acc[nt][0]), s1 = silu_f(acc[nt][1]);
      float s2 = silu_f(acc[nt][2]), s3 = silu_f(acc[nt][3]);
      pk[nt][0] = cvt_pk_bf16(s0, s1);
      pk[nt][1] = cvt_pk_bf16(s2, s3);
    }

    // ---- GEMM2: tc^T, C-init = coord_b1; a2 gathered via bpermute ----
    #pragma unroll
    for (int nt = 0; nt < 8; ++nt)
      acc[nt] = *(const f32x4*)(cb1sh + nt*16 + lgrp*4);
    #pragma unroll    // FULL unroll: pk[] indices must be compile-time (scratch rule)
    for (int ks2 = 0; ks2 < 4; ++ks2) {
      unsigned g[4];
      #pragma unroll
      for (int cg = 0; cg < 2; ++cg)
        #pragma unroll
        for (int p = 0; p < 2; ++p) {
          int a = cg ? adr1 : adr0;
          unsigned vlo = (unsigned)__builtin_amdgcn_ds_bpermute(a, (int)pk[2*ks2][p]);
          unsigned vhi = (unsigned)__builtin_amdgcn_ds_bpermute(a, (int)pk[2*ks2+1][p]);
          g[cg*2+p] = (lgrp < 2) ? vlo : vhi;
        }
      union { unsigned u[4]; bf16x8 v; } cvt;
      cvt.u[0] = g[0]; cvt.u[1] = g[1]; cvt.u[2] = g[2]; cvt.u[3] = g[3];
      bf16x8 a2 = cvt.v;
      #pragma unroll
      for (int nt = 0; nt < 8; ++nt) {
        bf16x8 bw = *(const bf16x8*)(C1s + ((ks2*8+nt)*512 + lane*8)*2);
        acc[nt] = MFMA(bw, a2, acc[nt]);
      }
    }

    // ---- epilogue: cw = silu(tc^T)·c2 summed over rows; rows split by lgrp ----
    float pcw = 0.f;
    #pragma unroll
    for (int nt = 0; nt < 8; ++nt) {
      f32x4 c2v = *(const f32x4*)(c2sh + nt*16 + lgrp*4);
      #pragma unroll
      for (int e = 0; e < 4; ++e)
        pcw += silu_f(acc[nt][e]) * c2v[e];
    }
    pcw += __shfl_xor(pcw, 16, 64);
    pcw += __shfl_xor(pcw, 32, 64);
    float cw = pcw + cb2;
    float s = cw * __builtin_amdgcn_rcpf(__builtin_amdgcn_sqrtf(rad) + 1.0f);
    agg0 += d0*s; agg1 += d1*s;
  }

  // each 16-lane group independently holds all-64-edge partials (edge=lid per ct)
  agg0 += __shfl_xor(agg0, 1, 64); agg1 += __shfl_xor(agg1, 1, 64);
  agg0 += __shfl_xor(agg0, 2, 64); agg1 += __shfl_xor(agg1, 2, 64);
  agg0 += __shfl_xor(agg0, 4, 64); agg1 += __shfl_xor(agg1, 4, 64);
  agg0 += __shfl_xor(agg0, 8, 64); agg1 += __shfl_xor(agg1, 8, 64);

  if (lane == 0) {
    float mu0 = baseo[r*2+0] + agg0;
    float mu1 = baseo[r*2+1] + agg1;
    float ls0 = log_std[0], ls1 = log_std[1];
    float e0 = eps[r*2+0], e1 = eps[r*2+1];
    const float C = 0.9189385332046727f; // 0.5*log(2*pi)
    out[r*4+0] = mu0 + __expf(ls0)*e0;
    out[r*4+1] = mu1 + __expf(ls1)*e1;
    out[r*4+2] = -0.5f*e0*e0 - ls0 - C;
    out[r*4+3] = -0.5f*e1*e1 - ls1 - C;
  }
}

extern "C" void kernel_launch(void* const* d_in, const int* in_sizes, int n_in,
                              void* d_out, int out_size, void* d_ws, size_t ws_size,
                              hipStream_t stream) {
  const float* obs      = (const float*)d_in[0];
  const float* eps      = (const float*)d_in[1];
  const float* embed_w  = (const float*)d_in[2];
  const float* embed_b  = (const float*)d_in[3];
  const float* edge_w1  = (const float*)d_in[4];
  const float* edge_b1  = (const float*)d_in[5];
  const float* edge_w2  = (const float*)d_in[6];
  const float* edge_b2  = (const float*)d_in[7];
  const float* coord_w1 = (const float*)d_in[8];
  const float* coord_b1 = (const float*)d_in[9];
  const float* coord_w2 = (const float*)d_in[10];
  const float* coord_b2 = (const float*)d_in[11];
  const float* velm_w1  = (const float*)d_in[12];
  const float* velm_b1  = (const float*)d_in[13];
  const float* velm_w2  = (const float*)d_in[14];
  const float* velm_b2  = (const float*)d_in[15];
  const float* mlp_w1   = (const float*)d_in[20];
  const float* mlp_b1   = (const float*)d_in[21];
  const float* mlp_w2   = (const float*)d_in[22];
  const float* mlp_b2   = (const float*)d_in[23];
  const float* mlp_w3   = (const float*)d_in[24];
  const float* mlp_b3   = (const float*)d_in[25];
  const float* log_std  = (const float*)d_in[26];
  char* ws = (char*)d_ws;
  float* out = (float*)d_out;

  // allow >64KB dynamic LDS for k_edge (host-side, idempotent, capture-safe)
  hipFuncSetAttribute((const void*)k_edge,
                      hipFuncAttributeMaxDynamicSharedMemorySize, L_TOTAL);

  hipLaunchKernelGGL(k_prep, dim3(128), dim3(128), 0, stream,
                     edge_w1, edge_w2, coord_w1, velm_w1, mlp_w1, mlp_w2, embed_w, ws);
  hipLaunchKernelGGL(k_node, dim3(512), dim3(64), 0, stream,
                     obs, embed_b, edge_b1, velm_b1, velm_w2, velm_b2,
                     mlp_b1, mlp_b2, mlp_w3, mlp_b3, ws);
  hipLaunchKernelGGL(k_edge, dim3(1024), dim3(512), L_TOTAL, stream,
                     obs, eps, edge_b2, coord_b1, coord_w2, coord_b2, log_std, ws, out);
}